// Round 15
// baseline (168.624 us; speedup 1.0000x reference)
//
#include <hip/hip_runtime.h>
#include <hip/hip_bf16.h>

// ---------------------------------------------------------------------------
// AttentionLayer round 14  ( = round 13, attn KVBLK 32 -> 64 per iteration )
//  - attn: QBLK=32, 4 waves/256thr, grid (288,2). Each iteration processes a
//    PAIR of 32-j tiles with ONE merged softmax (one max tree/permlane/
//    rescale-check/sum-permlane per 64 scores). 36 iterations instead of 72.
//    K prefetched one pair ahead; V loaded at iteration top (softmax covers
//    L2 latency). launch_bounds(256,2) -> 256 VGPR cap, no spill.
//  - convs/qkv byte-identical to round 13/11/5.
// ---------------------------------------------------------------------------

using short8 = __attribute__((ext_vector_type(8))) short;   // 8 bf16
using f32x4  = __attribute__((ext_vector_type(4))) float;
using f32x16 = __attribute__((ext_vector_type(16))) float;
using u32x4  = __attribute__((ext_vector_type(4))) unsigned;
typedef unsigned u32;
typedef unsigned short ushort;

#define NPIX 9216
#define PW 98
#define PLANE 9604            // fp32 padded plane (98*98)
#define PLANEB 9608           // bf16 padded plane, padded to 8 for b128 align
#define SEG 240               // conv staged window
#define LOG2E 1.44269504088896340736f

__device__ __forceinline__ ushort f2bf(float f) {
  u32 x = __builtin_bit_cast(u32, f);
  return (ushort)((x + 0x7fffu + ((x >> 16) & 1u)) >> 16);
}
__device__ __forceinline__ float bf2f(ushort h) {
  return __builtin_bit_cast(float, (u32)h << 16);
}
__device__ __forceinline__ float max3f(float a, float b, float c) {
  float d;
  asm("v_max3_f32 %0, %1, %2, %3" : "=v"(d) : "v"(a), "v"(b), "v"(c));
  return d;
}

// ---------------- weight prep: OIHW fp32 -> frag-linear bf16 hi/lo ----------
__global__ __launch_bounds__(256) void wprep(
    const float* __restrict__ w_pre, const float* __restrict__ w_fin,
    ushort* __restrict__ fpre, ushort* __restrict__ ffin)
{
  const int i = blockIdx.x * 256 + threadIdx.x;    // [0, 36864)
  const float* w = blockIdx.y ? w_fin : w_pre;
  ushort* dst    = blockIdx.y ? ffin : fpre;
  const int kk = i & 7, l = (i >> 3) & 63, cot = (i >> 9) & 1;
  const int chunk = (i >> 10) & 3, tap = i >> 12;
  const int co = cot * 32 + (l & 31);
  const int ci = chunk * 16 + 8 * (l >> 5) + kk;
  const float wv = w[co * 576 + ci * 9 + tap];
  const ushort h = f2bf(wv);
  const ushort lo = f2bf(wv - bf2f(h));
  const int base = tap * 8192 + chunk * 2048 + cot * 1024 + l * 8 + kk;
  dst[base] = h;
  dst[base + 512] = lo;
}

// ---------------- pad+split: x fp32 [96x96] -> xh/xl bf16 [98x98] interior --
__global__ __launch_bounds__(256) void pad_split(
    const float* __restrict__ in, ushort* __restrict__ xh, ushort* __restrict__ xl)
{
  const int plane = blockIdx.x;   // 0..127
  const float* src = in + (size_t)plane * 9216;
  const size_t dbase = (size_t)plane * PLANEB;
  for (int idx = threadIdx.x; idx < 9216; idx += 256) {
    const int y = idx / 96, x = idx - y * 96;
    const float v = src[idx];
    const ushort h = f2bf(v);
    const size_t d = dbase + (y + 1) * PW + x + 1;
    xh[d] = h;
    xl[d] = f2bf(v - bf2f(h));
  }
}

// ---------------- conv3x3 + BN + ReLU via MFMA (split-bf16, 4 products) -----
template <bool PADOUT>
__global__ __launch_bounds__(128) void conv3x3_mfma(
    const ushort* __restrict__ xh, const ushort* __restrict__ xl,
    const ushort* __restrict__ wfrag,
    const float* __restrict__ gg, const float* __restrict__ bb_,
    const float* __restrict__ mm, const float* __restrict__ vv,
    float* __restrict__ outp)
{
  __shared__ ushort stage[2][SEG][18];   // [hl][e][ci], 36B rows (bank-clean)
  __shared__ float scb[64], shb[64];
  const int n0  = blockIdx.x * 32;
  const int b   = blockIdx.y;
  const int tid = threadIdx.x;
  const int wm  = tid >> 6;
  const int lane = tid & 63;
  const int li = lane & 31, hi = lane >> 5;

  if (tid < 64) {
    const float sc = gg[tid] * rsqrtf(vv[tid] + 1e-5f);
    scb[tid] = sc;
    shb[tid] = bb_[tid] - mm[tid] * sc;
  }

  f32x16 acc = {};
  const int sbase = n0 - 8;

  for (int chunk = 0; chunk < 4; ++chunk) {
    __syncthreads();
#pragma unroll
    for (int it = 0; it < 8; ++it) {
      const int item = tid + it * 128;
      if (item < 960) {
        const int pl   = item >= 480;
        const int rem  = pl ? item - 480 : item;
        const int eblk = rem >> 4;
        const int ci   = rem & 15;
        const ushort* src = (pl ? xl : xh) +
            (size_t)(b * 64 + chunk * 16 + ci) * PLANEB + sbase + eblk * 8;
        const short8 v = *(const short8*)src;
#pragma unroll
        for (int j = 0; j < 8; ++j) stage[pl][eblk * 8 + j][ci] = (ushort)v[j];
      }
    }
    __syncthreads();

    const ushort* wb0 = wfrag + (size_t)(chunk * 2048 + wm * 1024 + lane * 8);
    short8 ah = *(const short8*)(wb0);
    short8 al = *(const short8*)(wb0 + 512);
#pragma unroll
    for (int tap = 0; tap < 9; ++tap) {
      const int eoff = (tap / 3) * PW + (tap % 3) + 7 + li;
      const short8 bh = *(const short8*)&stage[0][eoff][hi * 8];
      const short8 bl = *(const short8*)&stage[1][eoff][hi * 8];
      short8 ahn, aln;
      if (tap < 8) {
        const ushort* wbn = wb0 + (size_t)(tap + 1) * 8192;
        ahn = *(const short8*)(wbn);
        aln = *(const short8*)(wbn + 512);
      }
      acc = __builtin_amdgcn_mfma_f32_32x32x16_bf16(ah, bh, acc, 0, 0, 0);
      acc = __builtin_amdgcn_mfma_f32_32x32x16_bf16(ah, bl, acc, 0, 0, 0);
      acc = __builtin_amdgcn_mfma_f32_32x32x16_bf16(al, bh, acc, 0, 0, 0);
      acc = __builtin_amdgcn_mfma_f32_32x32x16_bf16(al, bl, acc, 0, 0, 0);
      if (tap < 8) { ah = ahn; al = aln; }
    }
  }

  const int pix = n0 + li;
  const int y = pix / PW;
  const int x = pix - y * PW;
  if (x >= 1 && x <= 96) {
#pragma unroll
    for (int r = 0; r < 16; ++r) {
      const int co = wm * 32 + (r & 3) + 8 * (r >> 2) + 4 * hi;
      const float val = fmaxf(scb[co] * acc[r] + shb[co], 0.f);
      if (PADOUT)
        outp[(size_t)(b * 64 + co) * PLANE + pix + PW] = val;
      else
        outp[(size_t)(b * 64 + co) * 9216 + y * 96 + (x - 1)] = val;
    }
  }
}

// ---------------- 1x1 q/k/v as bf16 MFMA GEMM -------------------------------
// cot 0 = q (x LOG2E) -> qsp[N][32] (hi 0..15, lo 16..31); 1 = k -> ksp same;
// 2..5 = v channel-quarters -> vfrag fragment-linear.
__global__ __launch_bounds__(64) void qkv_kernel(
    const float* __restrict__ x1p,
    const float* __restrict__ wq, const float* __restrict__ bq,
    const float* __restrict__ wk, const float* __restrict__ bk,
    const float* __restrict__ wv, const float* __restrict__ bv,
    ushort* __restrict__ qsp, ushort* __restrict__ ksp,
    ushort* __restrict__ vfrag)
{
  const int pix0 = blockIdx.x * 16;
  const int cot  = blockIdx.y;
  const int b    = blockIdx.z;
  const int lane = threadIdx.x;
  const int g    = lane >> 4;
  const int col  = lane & 15;

  const float* wr;
  const float* bias;
  if (cot == 0)      { wr = wq + col * 64; bias = bq; }
  else if (cot == 1) { wr = wk + col * 64; bias = bk; }
  else               { wr = wv + ((cot - 2) * 16 + col) * 64; bias = bv + (cot - 2) * 16; }

  const int yy = pix0 / 96, xx = pix0 - yy * 96;
  const int ro = (yy + 1) * PW + xx + 1;

  f32x4 acc = (f32x4){0.f, 0.f, 0.f, 0.f};
  const float* xb = x1p + (size_t)b * 64 * PLANE;
#pragma unroll
  for (int kt = 0; kt < 2; ++kt) {
    const float4 wa = *(const float4*)(wr + kt * 32 + 8 * g);
    const float4 wb2 = *(const float4*)(wr + kt * 32 + 8 * g + 4);
    short8 af;
    af[0] = (short)f2bf(wa.x); af[1] = (short)f2bf(wa.y);
    af[2] = (short)f2bf(wa.z); af[3] = (short)f2bf(wa.w);
    af[4] = (short)f2bf(wb2.x); af[5] = (short)f2bf(wb2.y);
    af[6] = (short)f2bf(wb2.z); af[7] = (short)f2bf(wb2.w);
    short8 bf;
#pragma unroll
    for (int jj = 0; jj < 8; ++jj)
      bf[jj] = (short)f2bf(xb[(size_t)(kt * 32 + 8 * g + jj) * PLANE + ro + col]);
    acc = __builtin_amdgcn_mfma_f32_16x16x32_bf16(af, bf, acc, 0, 0, 0);
  }
  if (cot < 2) {
    ushort* dst = (cot == 0 ? qsp : ksp) + ((size_t)(b * NPIX + pix0 + col)) * 32;
    const float scl = (cot == 0) ? LOG2E : 1.f;
#pragma unroll
    for (int r = 0; r < 4; ++r) {
      const int cl = 4 * g + r;
      const float val = (acc[r] + bias[cl]) * scl;
      const ushort h = f2bf(val);
      dst[cl] = h;
      dst[16 + cl] = f2bf(val - bf2f(h));
    }
  } else {
    ushort* dst = vfrag + (size_t)b * 589824;
    const int pix = pix0 + col;
    const int jt = pix >> 5, ks = (pix >> 4) & 1;
    const int lhalf = 32 * ((pix >> 3) & 1);
    const int kk = pix & 7;
#pragma unroll
    for (int r = 0; r < 4; ++r) {
      const int cl = 4 * g + r;
      const int c = (cot - 2) * 16 + cl;
      const int h = c >> 5;
      const int lA = (c & 31) + lhalf;
      dst[(size_t)((((jt * 2 + h) * 2 + ks) * 64 + lA)) * 8 + kk] =
          f2bf(acc[r] + bias[cl]);
    }
  }
}

// ---------------- flash attention, QBLK=32, KVBLK=64/iter, 4-wave j-split ---
// grid (288, 2), block 256. Wave w: 36 pair-iterations over j in
// [w*2304, (w+1)*2304). One merged softmax per 64 scores.
__global__ __launch_bounds__(256, 2) void attn_kernel(
    const ushort* __restrict__ qsp, const ushort* __restrict__ ksp,
    const ushort* __restrict__ vfrag, const float* __restrict__ x1p,
    const float* __restrict__ gamma_p,
    ushort* __restrict__ ofh, ushort* __restrict__ ofl)
{
  __shared__ float2 mlb[4][32];
  __shared__ float obuf[32][65];
  __shared__ float lbuf[32];

  const int b   = blockIdx.y;
  const int i0  = blockIdx.x * 32;
  const int tid = threadIdx.x;
  const int w   = tid >> 6;
  const int lane = tid & 63;
  const int li  = lane & 31;
  const int hi  = lane >> 5;

  for (int idx = tid; idx < 32 * 65; idx += 256) ((float*)obuf)[idx] = 0.f;
  if (tid < 32) lbuf[tid] = 0.f;
  __syncthreads();

  const ushort* kb    = ksp + (size_t)b * NPIX * 32;
  const ushort* vbase = vfrag + (size_t)b * 589824;

  const ushort* qrow = qsp + ((size_t)b * NPIX + i0 + li) * 32 + 8 * hi;
  const short8 qfh = *(const short8*)(qrow);
  const short8 qfl = *(const short8*)(qrow + 16);

  float m = -INFINITY;
  float lsum = 0.f;
  f32x16 acc[2] = {};

  const int jt0 = w * 72;                               // 72 tiles = 36 pairs
  const ushort* kptr = kb + (size_t)(jt0 * 32 + li) * 32 + 8 * hi;
  const ushort* vptr = vbase + ((size_t)(jt0 * 4) * 64 + lane) * 8;

  const f32x16 zf = {};

  // prologue: K pair 0 in regs
  short8 kh0 = *(const short8*)kptr;
  short8 kl0 = *(const short8*)(kptr + 16);
  short8 kh1 = *(const short8*)(kptr + 1024);
  short8 kl1 = *(const short8*)(kptr + 1040);

  for (int t = 0; t < 36; ++t) {
    // V pair t loads (consumed after softmax, ~400cy later)
    short8 vA0 = *(const short8*)(vptr);
    short8 vA1 = *(const short8*)(vptr + 512);
    short8 vA2 = *(const short8*)(vptr + 1024);
    short8 vA3 = *(const short8*)(vptr + 1536);
    short8 vB0 = *(const short8*)(vptr + 2048);
    short8 vB1 = *(const short8*)(vptr + 2560);
    short8 vB2 = *(const short8*)(vptr + 3072);
    short8 vB3 = *(const short8*)(vptr + 3584);

    // QK for both tiles of this pair (K already in regs)
    f32x16 s0 = __builtin_amdgcn_mfma_f32_32x32x16_bf16(kh0, qfh, zf, 0, 0, 0);
    s0 = __builtin_amdgcn_mfma_f32_32x32x16_bf16(kl0, qfh, s0, 0, 0, 0);
    s0 = __builtin_amdgcn_mfma_f32_32x32x16_bf16(kh0, qfl, s0, 0, 0, 0);
    f32x16 s1 = __builtin_amdgcn_mfma_f32_32x32x16_bf16(kh1, qfh, zf, 0, 0, 0);
    s1 = __builtin_amdgcn_mfma_f32_32x32x16_bf16(kl1, qfh, s1, 0, 0, 0);
    s1 = __builtin_amdgcn_mfma_f32_32x32x16_bf16(kh1, qfl, s1, 0, 0, 0);

    // prefetch K pair t+1 (consumed next iteration, ~700cy later)
    if (t < 35) {
      kptr += 2048;
      kh0 = *(const short8*)kptr;
      kl0 = *(const short8*)(kptr + 16);
      kh1 = *(const short8*)(kptr + 1024);
      kl1 = *(const short8*)(kptr + 1040);
    }
    if (t < 35) vptr += 4096;

    // ---- merged softmax over 64 scores ----
    float p0 = max3f(s0[0], s0[1], s0[2]);
    float p1 = max3f(s0[3], s0[4], s0[5]);
    float p2 = max3f(s0[6], s0[7], s0[8]);
    float p3 = max3f(s0[9], s0[10], s0[11]);
    float p4 = max3f(s0[12], s0[13], s0[14]);
    float p5 = max3f(s1[0], s1[1], s1[2]);
    float p6 = max3f(s1[3], s1[4], s1[5]);
    float p7 = max3f(s1[6], s1[7], s1[8]);
    float p8 = max3f(s1[9], s1[10], s1[11]);
    float p9 = max3f(s1[12], s1[13], s1[14]);
    float pa = fmaxf(s0[15], s1[15]);
    p0 = max3f(p0, p1, p2);
    p3 = max3f(p3, p4, p5);
    p6 = max3f(p6, p7, p8);
    p9 = max3f(p9, pa, p0);
    float pm = max3f(p3, p6, p9);
    {
      float o = pm;
      asm("v_permlane32_swap_b32 %0, %1" : "+v"(o), "+v"(pm));
      pm = fmaxf(pm, o);
    }

    if (__any(pm > m + 8.f)) {   // defer-max rescale (T13)
      const float mnew = fmaxf(m, pm);
      const float corr = __builtin_amdgcn_exp2f(m - mnew);
      lsum *= corr;
      acc[0] *= corr;
      acc[1] *= corr;
      m = mnew;
    }

#pragma unroll
    for (int r = 0; r < 16; ++r) s0[r] = __builtin_amdgcn_exp2f(s0[r] - m);
#pragma unroll
    for (int r = 0; r < 16; ++r) s1[r] = __builtin_amdgcn_exp2f(s1[r] - m);
    float ps = ((((s0[0] + s0[1]) + (s0[2] + s0[3])) + ((s0[4] + s0[5]) + (s0[6] + s0[7]))) +
                (((s0[8] + s0[9]) + (s0[10] + s0[11])) + ((s0[12] + s0[13]) + (s0[14] + s0[15])))) +
               ((((s1[0] + s1[1]) + (s1[2] + s1[3])) + ((s1[4] + s1[5]) + (s1[6] + s1[7]))) +
                (((s1[8] + s1[9]) + (s1[10] + s1[11])) + ((s1[12] + s1[13]) + (s1[14] + s1[15]))));
    {
      float o = ps;
      asm("v_permlane32_swap_b32 %0, %1" : "+v"(o), "+v"(ps));
      ps = ps + o;
    }
    lsum += ps;

    // pack both tiles' P to bf16 PV B-frags (T12)
    u32 a01, a23, a45, a67, b01, b23, b45, b67;
    u32 c01, c23, c45, c67, d01, d23, d45, d67;
    asm("v_cvt_pk_bf16_f32 %0, %1, %2" : "=v"(a01) : "v"(s0[0]),  "v"(s0[1]));
    asm("v_cvt_pk_bf16_f32 %0, %1, %2" : "=v"(a23) : "v"(s0[2]),  "v"(s0[3]));
    asm("v_cvt_pk_bf16_f32 %0, %1, %2" : "=v"(a45) : "v"(s0[4]),  "v"(s0[5]));
    asm("v_cvt_pk_bf16_f32 %0, %1, %2" : "=v"(a67) : "v"(s0[6]),  "v"(s0[7]));
    asm("v_cvt_pk_bf16_f32 %0, %1, %2" : "=v"(b01) : "v"(s0[8]),  "v"(s0[9]));
    asm("v_cvt_pk_bf16_f32 %0, %1, %2" : "=v"(b23) : "v"(s0[10]), "v"(s0[11]));
    asm("v_cvt_pk_bf16_f32 %0, %1, %2" : "=v"(b45) : "v"(s0[12]), "v"(s0[13]));
    asm("v_cvt_pk_bf16_f32 %0, %1, %2" : "=v"(b67) : "v"(s0[14]), "v"(s0[15]));
    asm("v_permlane32_swap_b32 %0, %1" : "+v"(a45), "+v"(a01));
    asm("v_permlane32_swap_b32 %0, %1" : "+v"(a67), "+v"(a23));
    asm("v_permlane32_swap_b32 %0, %1" : "+v"(b45), "+v"(b01));
    asm("v_permlane32_swap_b32 %0, %1" : "+v"(b67), "+v"(b23));
    asm("v_cvt_pk_bf16_f32 %0, %1, %2" : "=v"(c01) : "v"(s1[0]),  "v"(s1[1]));
    asm("v_cvt_pk_bf16_f32 %0, %1, %2" : "=v"(c23) : "v"(s1[2]),  "v"(s1[3]));
    asm("v_cvt_pk_bf16_f32 %0, %1, %2" : "=v"(c45) : "v"(s1[4]),  "v"(s1[5]));
    asm("v_cvt_pk_bf16_f32 %0, %1, %2" : "=v"(c67) : "v"(s1[6]),  "v"(s1[7]));
    asm("v_cvt_pk_bf16_f32 %0, %1, %2" : "=v"(d01) : "v"(s1[8]),  "v"(s1[9]));
    asm("v_cvt_pk_bf16_f32 %0, %1, %2" : "=v"(d23) : "v"(s1[10]), "v"(s1[11]));
    asm("v_cvt_pk_bf16_f32 %0, %1, %2" : "=v"(d45) : "v"(s1[12]), "v"(s1[13]));
    asm("v_cvt_pk_bf16_f32 %0, %1, %2" : "=v"(d67) : "v"(s1[14]), "v"(s1[15]));
    asm("v_permlane32_swap_b32 %0, %1" : "+v"(c45), "+v"(c01));
    asm("v_permlane32_swap_b32 %0, %1" : "+v"(c67), "+v"(c23));
    asm("v_permlane32_swap_b32 %0, %1" : "+v"(d45), "+v"(d01));
    asm("v_permlane32_swap_b32 %0, %1" : "+v"(d67), "+v"(d23));
    const short8 pfA1 = __builtin_bit_cast(short8, (u32x4){a01, a23, a45, a67});
    const short8 pfA2 = __builtin_bit_cast(short8, (u32x4){b01, b23, b45, b67});
    const short8 pfB1 = __builtin_bit_cast(short8, (u32x4){c01, c23, c45, c67});
    const short8 pfB2 = __builtin_bit_cast(short8, (u32x4){d01, d23, d45, d67});

    acc[0] = __builtin_amdgcn_mfma_f32_32x32x16_bf16(vA0, pfA1, acc[0], 0, 0, 0);
    acc[0] = __builtin_amdgcn_mfma_f32_32x32x16_bf16(vA1, pfA2, acc[0], 0, 0, 0);
    acc[1] = __builtin_amdgcn_mfma_f32_32x32x16_bf16(vA2, pfA1, acc[1], 0, 0, 0);
    acc[1] = __builtin_amdgcn_mfma_f32_32x32x16_bf16(vA3, pfA2, acc[1], 0, 0, 0);
    acc[0] = __builtin_amdgcn_mfma_f32_32x32x16_bf16(vB0, pfB1, acc[0], 0, 0, 0);
    acc[0] = __builtin_amdgcn_mfma_f32_32x32x16_bf16(vB1, pfB2, acc[0], 0, 0, 0);
    acc[1] = __builtin_amdgcn_mfma_f32_32x32x16_bf16(vB2, pfB1, acc[1], 0, 0, 0);
    acc[1] = __builtin_amdgcn_mfma_f32_32x32x16_bf16(vB3, pfB2, acc[1], 0, 0, 0);
  }

  // ---- merge 4 waves ----
  if (hi == 0) { float2 t2; t2.x = m; t2.y = lsum; mlb[w][li] = t2; }
  __syncthreads();
  float M = -INFINITY;
#pragma unroll
  for (int ww = 0; ww < 4; ++ww) M = fmaxf(M, mlb[ww][li].x);
  const float f = __builtin_amdgcn_exp2f(m - M);
  if (hi == 0) atomicAdd(&lbuf[li], lsum * f);
#pragma unroll
  for (int hh = 0; hh < 2; ++hh)
#pragma unroll
    for (int r = 0; r < 16; ++r) {
      const int c = (r & 3) + 8 * (r >> 2) + 4 * hi + 32 * hh;
      atomicAdd(&obuf[li][c], acc[hh][r] * f);
    }
  __syncthreads();

  const float gm = gamma_p[0];
  for (int idx = tid; idx < 2048; idx += 256) {
    const int il = idx & 31, c = idx >> 5;
    const int p = i0 + il;
    const int y = p / 96, x = p - y * 96;
    const int ro = (y + 1) * PW + x + 1;
    const float val = obuf[il][c] / lbuf[il] * gm +
                      x1p[(size_t)(b * 64 + c) * PLANE + ro];
    const ushort h = f2bf(val);
    const size_t d = (size_t)(b * 64 + c) * PLANEB + ro;
    ofh[d] = h;
    ofl[d] = f2bf(val - bf2f(h));
  }
}

// ---------------------------------------------------------------------------
extern "C" void kernel_launch(void* const* d_in, const int* in_sizes, int n_in,
                              void* d_out, int out_size, void* d_ws, size_t ws_size,
                              hipStream_t stream) {
  const float* x      = (const float*)d_in[0];
  const float* w_pre  = (const float*)d_in[1];
  const float* bn1_g  = (const float*)d_in[2];
  const float* bn1_b  = (const float*)d_in[3];
  const float* bn1_m  = (const float*)d_in[4];
  const float* bn1_v  = (const float*)d_in[5];
  const float* wq     = (const float*)d_in[6];
  const float* bq     = (const float*)d_in[7];
  const float* wk     = (const float*)d_in[8];
  const float* bk     = (const float*)d_in[9];
  const float* wv     = (const float*)d_in[10];
  const float* bv     = (const float*)d_in[11];
  const float* w_fin  = (const float*)d_in[12];
  const float* bn2_g  = (const float*)d_in[13];
  const float* bn2_b  = (const float*)d_in[14];
  const float* bn2_m  = (const float*)d_in[15];
  const float* bn2_v  = (const float*)d_in[16];
  const float* gamma  = (const float*)d_in[17];
  float* out = (float*)d_out;

  char* ws = (char*)d_ws;
  float*  x1p  = (float*)(ws);                       // 4,917,248 B
  ushort* xh   = (ushort*)(ws + 4917248);            // 2,459,648 B
  ushort* xl   = (ushort*)(ws + 7376896);            // 2,459,648 B
  ushort* qsp  = (ushort*)(ws + 9836544);            // 1,179,648 B
  ushort* ksp  = (ushort*)(ws + 11016192);           // 1,179,648 B
  ushort* vfr  = (ushort*)(ws + 12195840);           // 2,359,296 B
  ushort* fpre = (ushort*)(ws + 14555136);           //   147,456 B
  ushort* ffin = (ushort*)(ws + 14702592);           //   147,456 B -> end 14,850,048
  ushort* ofh = xh;   // xh/xl dead after conv1; reuse for attn output planes
  ushort* ofl = xl;

  // zero bf16 plane region (pad rings must be 0; interiors rewritten each call)
  hipMemsetAsync(ws + 4917248, 0, 4919296, stream);

  wprep<<<dim3(144, 2), 256, 0, stream>>>(w_pre, w_fin, fpre, ffin);
  pad_split<<<dim3(128), 256, 0, stream>>>(x, xh, xl);
  conv3x3_mfma<true><<<dim3(294, 2), 128, 0, stream>>>(
      xh, xl, fpre, bn1_g, bn1_b, bn1_m, bn1_v, x1p);
  qkv_kernel<<<dim3(576, 6, 2), 64, 0, stream>>>(
      x1p, wq, bq, wk, bk, wv, bv, qsp, ksp, vfr);
  attn_kernel<<<dim3(288, 2), 256, 0, stream>>>(
      qsp, ksp, vfr, x1p, gamma, ofh, ofl);
  conv3x3_mfma<false><<<dim3(294, 2), 128, 0, stream>>>(
      ofh, ofl, ffin, bn2_g, bn2_b, bn2_m, bn2_v, out);
}

// Round 16
// 167.407 us; speedup vs baseline: 1.0073x; 1.0073x over previous
//
#include <hip/hip_runtime.h>
#include <hip/hip_bf16.h>

// ---------------------------------------------------------------------------
// AttentionLayer round 15  ( = round 13 + non-temporal epilogue streams )
//  - attn: QBLK=32, 4 waves, SW-pipelined QK (r13, 94.9us). NEW: epilogue
//    x1p residual reads and ofh/ofl stores are NON-TEMPORAL -> they no longer
//    evict K/V from the per-XCD L2 (FETCH was 19.6MB vs 4.7MB compulsory;
//    stream pollution made in-loop K/V loads ~900cy HBM misses).
//  - convs/qkv byte-identical to round 13/11/5.
// ---------------------------------------------------------------------------

using short8 = __attribute__((ext_vector_type(8))) short;   // 8 bf16
using f32x4  = __attribute__((ext_vector_type(4))) float;
using f32x16 = __attribute__((ext_vector_type(16))) float;
using u32x4  = __attribute__((ext_vector_type(4))) unsigned;
typedef unsigned u32;
typedef unsigned short ushort;

#define NPIX 9216
#define PW 98
#define PLANE 9604            // fp32 padded plane (98*98)
#define PLANEB 9608           // bf16 padded plane, padded to 8 for b128 align
#define SEG 240               // conv staged window
#define LOG2E 1.44269504088896340736f

__device__ __forceinline__ ushort f2bf(float f) {
  u32 x = __builtin_bit_cast(u32, f);
  return (ushort)((x + 0x7fffu + ((x >> 16) & 1u)) >> 16);
}
__device__ __forceinline__ float bf2f(ushort h) {
  return __builtin_bit_cast(float, (u32)h << 16);
}
__device__ __forceinline__ float max3f(float a, float b, float c) {
  float d;
  asm("v_max3_f32 %0, %1, %2, %3" : "=v"(d) : "v"(a), "v"(b), "v"(c));
  return d;
}

// ---------------- weight prep: OIHW fp32 -> frag-linear bf16 hi/lo ----------
__global__ __launch_bounds__(256) void wprep(
    const float* __restrict__ w_pre, const float* __restrict__ w_fin,
    ushort* __restrict__ fpre, ushort* __restrict__ ffin)
{
  const int i = blockIdx.x * 256 + threadIdx.x;    // [0, 36864)
  const float* w = blockIdx.y ? w_fin : w_pre;
  ushort* dst    = blockIdx.y ? ffin : fpre;
  const int kk = i & 7, l = (i >> 3) & 63, cot = (i >> 9) & 1;
  const int chunk = (i >> 10) & 3, tap = i >> 12;
  const int co = cot * 32 + (l & 31);
  const int ci = chunk * 16 + 8 * (l >> 5) + kk;
  const float wv = w[co * 576 + ci * 9 + tap];
  const ushort h = f2bf(wv);
  const ushort lo = f2bf(wv - bf2f(h));
  const int base = tap * 8192 + chunk * 2048 + cot * 1024 + l * 8 + kk;
  dst[base] = h;
  dst[base + 512] = lo;
}

// ---------------- pad+split: x fp32 [96x96] -> xh/xl bf16 [98x98] interior --
__global__ __launch_bounds__(256) void pad_split(
    const float* __restrict__ in, ushort* __restrict__ xh, ushort* __restrict__ xl)
{
  const int plane = blockIdx.x;   // 0..127
  const float* src = in + (size_t)plane * 9216;
  const size_t dbase = (size_t)plane * PLANEB;
  for (int idx = threadIdx.x; idx < 9216; idx += 256) {
    const int y = idx / 96, x = idx - y * 96;
    const float v = src[idx];
    const ushort h = f2bf(v);
    const size_t d = dbase + (y + 1) * PW + x + 1;
    xh[d] = h;
    xl[d] = f2bf(v - bf2f(h));
  }
}

// ---------------- conv3x3 + BN + ReLU via MFMA (split-bf16, 4 products) -----
template <bool PADOUT>
__global__ __launch_bounds__(128) void conv3x3_mfma(
    const ushort* __restrict__ xh, const ushort* __restrict__ xl,
    const ushort* __restrict__ wfrag,
    const float* __restrict__ gg, const float* __restrict__ bb_,
    const float* __restrict__ mm, const float* __restrict__ vv,
    float* __restrict__ outp)
{
  __shared__ ushort stage[2][SEG][18];   // [hl][e][ci], 36B rows (bank-clean)
  __shared__ float scb[64], shb[64];
  const int n0  = blockIdx.x * 32;
  const int b   = blockIdx.y;
  const int tid = threadIdx.x;
  const int wm  = tid >> 6;
  const int lane = tid & 63;
  const int li = lane & 31, hi = lane >> 5;

  if (tid < 64) {
    const float sc = gg[tid] * rsqrtf(vv[tid] + 1e-5f);
    scb[tid] = sc;
    shb[tid] = bb_[tid] - mm[tid] * sc;
  }

  f32x16 acc = {};
  const int sbase = n0 - 8;

  for (int chunk = 0; chunk < 4; ++chunk) {
    __syncthreads();
#pragma unroll
    for (int it = 0; it < 8; ++it) {
      const int item = tid + it * 128;
      if (item < 960) {
        const int pl   = item >= 480;
        const int rem  = pl ? item - 480 : item;
        const int eblk = rem >> 4;
        const int ci   = rem & 15;
        const ushort* src = (pl ? xl : xh) +
            (size_t)(b * 64 + chunk * 16 + ci) * PLANEB + sbase + eblk * 8;
        const short8 v = *(const short8*)src;
#pragma unroll
        for (int j = 0; j < 8; ++j) stage[pl][eblk * 8 + j][ci] = (ushort)v[j];
      }
    }
    __syncthreads();

    const ushort* wb0 = wfrag + (size_t)(chunk * 2048 + wm * 1024 + lane * 8);
    short8 ah = *(const short8*)(wb0);
    short8 al = *(const short8*)(wb0 + 512);
#pragma unroll
    for (int tap = 0; tap < 9; ++tap) {
      const int eoff = (tap / 3) * PW + (tap % 3) + 7 + li;
      const short8 bh = *(const short8*)&stage[0][eoff][hi * 8];
      const short8 bl = *(const short8*)&stage[1][eoff][hi * 8];
      short8 ahn, aln;
      if (tap < 8) {
        const ushort* wbn = wb0 + (size_t)(tap + 1) * 8192;
        ahn = *(const short8*)(wbn);
        aln = *(const short8*)(wbn + 512);
      }
      acc = __builtin_amdgcn_mfma_f32_32x32x16_bf16(ah, bh, acc, 0, 0, 0);
      acc = __builtin_amdgcn_mfma_f32_32x32x16_bf16(ah, bl, acc, 0, 0, 0);
      acc = __builtin_amdgcn_mfma_f32_32x32x16_bf16(al, bh, acc, 0, 0, 0);
      acc = __builtin_amdgcn_mfma_f32_32x32x16_bf16(al, bl, acc, 0, 0, 0);
      if (tap < 8) { ah = ahn; al = aln; }
    }
  }

  const int pix = n0 + li;
  const int y = pix / PW;
  const int x = pix - y * PW;
  if (x >= 1 && x <= 96) {
#pragma unroll
    for (int r = 0; r < 16; ++r) {
      const int co = wm * 32 + (r & 3) + 8 * (r >> 2) + 4 * hi;
      const float val = fmaxf(scb[co] * acc[r] + shb[co], 0.f);
      if (PADOUT)
        outp[(size_t)(b * 64 + co) * PLANE + pix + PW] = val;
      else
        outp[(size_t)(b * 64 + co) * 9216 + y * 96 + (x - 1)] = val;
    }
  }
}

// ---------------- 1x1 q/k/v as bf16 MFMA GEMM -------------------------------
// cot 0 = q (x LOG2E) -> qsp[N][32] (hi 0..15, lo 16..31); 1 = k -> ksp same;
// 2..5 = v channel-quarters -> vfrag fragment-linear.
__global__ __launch_bounds__(64) void qkv_kernel(
    const float* __restrict__ x1p,
    const float* __restrict__ wq, const float* __restrict__ bq,
    const float* __restrict__ wk, const float* __restrict__ bk,
    const float* __restrict__ wv, const float* __restrict__ bv,
    ushort* __restrict__ qsp, ushort* __restrict__ ksp,
    ushort* __restrict__ vfrag)
{
  const int pix0 = blockIdx.x * 16;
  const int cot  = blockIdx.y;
  const int b    = blockIdx.z;
  const int lane = threadIdx.x;
  const int g    = lane >> 4;
  const int col  = lane & 15;

  const float* wr;
  const float* bias;
  if (cot == 0)      { wr = wq + col * 64; bias = bq; }
  else if (cot == 1) { wr = wk + col * 64; bias = bk; }
  else               { wr = wv + ((cot - 2) * 16 + col) * 64; bias = bv + (cot - 2) * 16; }

  const int yy = pix0 / 96, xx = pix0 - yy * 96;
  const int ro = (yy + 1) * PW + xx + 1;

  f32x4 acc = (f32x4){0.f, 0.f, 0.f, 0.f};
  const float* xb = x1p + (size_t)b * 64 * PLANE;
#pragma unroll
  for (int kt = 0; kt < 2; ++kt) {
    const float4 wa = *(const float4*)(wr + kt * 32 + 8 * g);
    const float4 wb2 = *(const float4*)(wr + kt * 32 + 8 * g + 4);
    short8 af;
    af[0] = (short)f2bf(wa.x); af[1] = (short)f2bf(wa.y);
    af[2] = (short)f2bf(wa.z); af[3] = (short)f2bf(wa.w);
    af[4] = (short)f2bf(wb2.x); af[5] = (short)f2bf(wb2.y);
    af[6] = (short)f2bf(wb2.z); af[7] = (short)f2bf(wb2.w);
    short8 bf;
#pragma unroll
    for (int jj = 0; jj < 8; ++jj)
      bf[jj] = (short)f2bf(xb[(size_t)(kt * 32 + 8 * g + jj) * PLANE + ro + col]);
    acc = __builtin_amdgcn_mfma_f32_16x16x32_bf16(af, bf, acc, 0, 0, 0);
  }
  if (cot < 2) {
    ushort* dst = (cot == 0 ? qsp : ksp) + ((size_t)(b * NPIX + pix0 + col)) * 32;
    const float scl = (cot == 0) ? LOG2E : 1.f;
#pragma unroll
    for (int r = 0; r < 4; ++r) {
      const int cl = 4 * g + r;
      const float val = (acc[r] + bias[cl]) * scl;
      const ushort h = f2bf(val);
      dst[cl] = h;
      dst[16 + cl] = f2bf(val - bf2f(h));
    }
  } else {
    ushort* dst = vfrag + (size_t)b * 589824;
    const int pix = pix0 + col;
    const int jt = pix >> 5, ks = (pix >> 4) & 1;
    const int lhalf = 32 * ((pix >> 3) & 1);
    const int kk = pix & 7;
#pragma unroll
    for (int r = 0; r < 4; ++r) {
      const int cl = 4 * g + r;
      const int c = (cot - 2) * 16 + cl;
      const int h = c >> 5;
      const int lA = (c & 31) + lhalf;
      dst[(size_t)((((jt * 2 + h) * 2 + ks) * 64 + lA)) * 8 + kk] =
          f2bf(acc[r] + bias[cl]);
    }
  }
}

// ---------------- flash attention, QBLK=32, 4-wave j-split, SW-pipelined ----
// grid (288, 2), block 256. Wave w: j in [w*2304, (w+1)*2304), 72 tiles of 32.
// Epilogue residual reads + output stores are NON-TEMPORAL (keep K/V in L2).
__global__ __launch_bounds__(256, 3) void attn_kernel(
    const ushort* __restrict__ qsp, const ushort* __restrict__ ksp,
    const ushort* __restrict__ vfrag, const float* __restrict__ x1p,
    const float* __restrict__ gamma_p,
    ushort* __restrict__ ofh, ushort* __restrict__ ofl)
{
  __shared__ float2 mlb[4][32];
  __shared__ float obuf[32][65];
  __shared__ float lbuf[32];

  const int b   = blockIdx.y;
  const int i0  = blockIdx.x * 32;
  const int tid = threadIdx.x;
  const int w   = tid >> 6;
  const int lane = tid & 63;
  const int li  = lane & 31;
  const int hi  = lane >> 5;

  for (int idx = tid; idx < 32 * 65; idx += 256) ((float*)obuf)[idx] = 0.f;
  if (tid < 32) lbuf[tid] = 0.f;
  __syncthreads();

  const ushort* kb    = ksp + (size_t)b * NPIX * 32;
  const ushort* vbase = vfrag + (size_t)b * 589824;

  const ushort* qrow = qsp + ((size_t)b * NPIX + i0 + li) * 32 + 8 * hi;
  const short8 qfh = *(const short8*)(qrow);
  const short8 qfl = *(const short8*)(qrow + 16);

  float m = -INFINITY;
  float lsum = 0.f;
  f32x16 acc[2] = {};

  const int jt0 = w * 72;
  const ushort* kptr = kb + (size_t)(jt0 * 32 + li) * 32 + 8 * hi;
  const ushort* vptr = vbase + ((size_t)(jt0 * 4) * 64 + lane) * 8;

  const f32x16 zf = {};

  // ---- prologue: s for tile 0; K(1) in regs; V(0) in regs ----
  short8 kh0 = *(const short8*)kptr;
  short8 kl0 = *(const short8*)(kptr + 16);
  f32x16 s = __builtin_amdgcn_mfma_f32_32x32x16_bf16(kh0, qfh, zf, 0, 0, 0);
  s = __builtin_amdgcn_mfma_f32_32x32x16_bf16(kl0, qfh, s, 0, 0, 0);
  s = __builtin_amdgcn_mfma_f32_32x32x16_bf16(kh0, qfl, s, 0, 0, 0);
  kptr += 1024;
  short8 kh_n = *(const short8*)kptr;        // K(1)
  short8 kl_n = *(const short8*)(kptr + 16);
  short8 vf00 = *(const short8*)(vptr);
  short8 vf01 = *(const short8*)(vptr + 512);
  short8 vf10 = *(const short8*)(vptr + 1024);
  short8 vf11 = *(const short8*)(vptr + 1536);

  for (int t = 0; t < 72; ++t) {
    // QK for tile t+1 issued NOW; retires under softmax(t)'s VALU work
    f32x16 s_next;
    if (t < 71) {
      s_next = __builtin_amdgcn_mfma_f32_32x32x16_bf16(kh_n, qfh, zf, 0, 0, 0);
      s_next = __builtin_amdgcn_mfma_f32_32x32x16_bf16(kl_n, qfh, s_next, 0, 0, 0);
      s_next = __builtin_amdgcn_mfma_f32_32x32x16_bf16(kh_n, qfl, s_next, 0, 0, 0);
    }

    // prefetch K(t+2), V(t+1)
    short8 kh_p, kl_p, v00n, v01n, v10n, v11n;
    if (t < 70) {
      kptr += 1024;
      kh_p = *(const short8*)kptr;
      kl_p = *(const short8*)(kptr + 16);
    }
    if (t < 71) {
      vptr += 2048;
      v00n = *(const short8*)(vptr);
      v01n = *(const short8*)(vptr + 512);
      v10n = *(const short8*)(vptr + 1024);
      v11n = *(const short8*)(vptr + 1536);
    }

    // ---- softmax on s (tile t) ----
    float pm, q1, q2, q3, q4;
    pm = max3f(s[0], s[1], s[2]);
    q1 = max3f(s[3], s[4], s[5]);
    q2 = max3f(s[6], s[7], s[8]);
    q3 = max3f(s[9], s[10], s[11]);
    q4 = max3f(s[12], s[13], s[14]);
    pm = max3f(pm, q1, q2);
    pm = max3f(pm, q3, q4);
    pm = fmaxf(pm, s[15]);
    {
      float o = pm;
      asm("v_permlane32_swap_b32 %0, %1" : "+v"(o), "+v"(pm));
      pm = fmaxf(pm, o);
    }

    if (__any(pm > m + 8.f)) {   // defer-max rescale (T13)
      const float mnew = fmaxf(m, pm);
      const float corr = __builtin_amdgcn_exp2f(m - mnew);
      lsum *= corr;
      acc[0] *= corr;
      acc[1] *= corr;
      m = mnew;
    }

#pragma unroll
    for (int r = 0; r < 16; ++r) s[r] = __builtin_amdgcn_exp2f(s[r] - m);
    float ps = (((s[0] + s[1]) + (s[2] + s[3])) + ((s[4] + s[5]) + (s[6] + s[7]))) +
               (((s[8] + s[9]) + (s[10] + s[11])) + ((s[12] + s[13]) + (s[14] + s[15])));
    {
      float o = ps;
      asm("v_permlane32_swap_b32 %0, %1" : "+v"(o), "+v"(ps));
      ps = ps + o;
    }
    lsum += ps;

    u32 c01, c23, c45, c67, d01, d23, d45, d67;
    asm("v_cvt_pk_bf16_f32 %0, %1, %2" : "=v"(c01) : "v"(s[0]),  "v"(s[1]));
    asm("v_cvt_pk_bf16_f32 %0, %1, %2" : "=v"(c23) : "v"(s[2]),  "v"(s[3]));
    asm("v_cvt_pk_bf16_f32 %0, %1, %2" : "=v"(c45) : "v"(s[4]),  "v"(s[5]));
    asm("v_cvt_pk_bf16_f32 %0, %1, %2" : "=v"(c67) : "v"(s[6]),  "v"(s[7]));
    asm("v_cvt_pk_bf16_f32 %0, %1, %2" : "=v"(d01) : "v"(s[8]),  "v"(s[9]));
    asm("v_cvt_pk_bf16_f32 %0, %1, %2" : "=v"(d23) : "v"(s[10]), "v"(s[11]));
    asm("v_cvt_pk_bf16_f32 %0, %1, %2" : "=v"(d45) : "v"(s[12]), "v"(s[13]));
    asm("v_cvt_pk_bf16_f32 %0, %1, %2" : "=v"(d67) : "v"(s[14]), "v"(s[15]));
    asm("v_permlane32_swap_b32 %0, %1" : "+v"(c45), "+v"(c01));
    asm("v_permlane32_swap_b32 %0, %1" : "+v"(c67), "+v"(c23));
    asm("v_permlane32_swap_b32 %0, %1" : "+v"(d45), "+v"(d01));
    asm("v_permlane32_swap_b32 %0, %1" : "+v"(d67), "+v"(d23));
    const short8 pf1 = __builtin_bit_cast(short8, (u32x4){c01, c23, c45, c67});
    const short8 pf2 = __builtin_bit_cast(short8, (u32x4){d01, d23, d45, d67});

    acc[0] = __builtin_amdgcn_mfma_f32_32x32x16_bf16(vf00, pf1, acc[0], 0, 0, 0);
    acc[0] = __builtin_amdgcn_mfma_f32_32x32x16_bf16(vf01, pf2, acc[0], 0, 0, 0);
    acc[1] = __builtin_amdgcn_mfma_f32_32x32x16_bf16(vf10, pf1, acc[1], 0, 0, 0);
    acc[1] = __builtin_amdgcn_mfma_f32_32x32x16_bf16(vf11, pf2, acc[1], 0, 0, 0);

    // rotate pipeline state
    if (t < 71) {
      s = s_next;
      vf00 = v00n; vf01 = v01n; vf10 = v10n; vf11 = v11n;
    }
    if (t < 70) { kh_n = kh_p; kl_n = kl_p; }
  }

  // ---- merge 4 waves ----
  if (hi == 0) { float2 t2; t2.x = m; t2.y = lsum; mlb[w][li] = t2; }
  __syncthreads();
  float M = -INFINITY;
#pragma unroll
  for (int ww = 0; ww < 4; ++ww) M = fmaxf(M, mlb[ww][li].x);
  const float f = __builtin_amdgcn_exp2f(m - M);
  if (hi == 0) atomicAdd(&lbuf[li], lsum * f);
#pragma unroll
  for (int hh = 0; hh < 2; ++hh)
#pragma unroll
    for (int r = 0; r < 16; ++r) {
      const int c = (r & 3) + 8 * (r >> 2) + 4 * hi + 32 * hh;
      atomicAdd(&obuf[li][c], acc[hh][r] * f);
    }
  __syncthreads();

  const float gm = gamma_p[0];
  for (int idx = tid; idx < 2048; idx += 256) {
    const int il = idx & 31, c = idx >> 5;
    const int p = i0 + il;
    const int y = p / 96, x = p - y * 96;
    const int ro = (y + 1) * PW + x + 1;
    const float res = __builtin_nontemporal_load(
        &x1p[(size_t)(b * 64 + c) * PLANE + ro]);
    const float val = obuf[il][c] / lbuf[il] * gm + res;
    const ushort h = f2bf(val);
    const size_t d = (size_t)(b * 64 + c) * PLANEB + ro;
    __builtin_nontemporal_store(h, &ofh[d]);
    __builtin_nontemporal_store(f2bf(val - bf2f(h)), &ofl[d]);
  }
}

// ---------------------------------------------------------------------------
extern "C" void kernel_launch(void* const* d_in, const int* in_sizes, int n_in,
                              void* d_out, int out_size, void* d_ws, size_t ws_size,
                              hipStream_t stream) {
  const float* x      = (const float*)d_in[0];
  const float* w_pre  = (const float*)d_in[1];
  const float* bn1_g  = (const float*)d_in[2];
  const float* bn1_b  = (const float*)d_in[3];
  const float* bn1_m  = (const float*)d_in[4];
  const float* bn1_v  = (const float*)d_in[5];
  const float* wq     = (const float*)d_in[6];
  const float* bq     = (const float*)d_in[7];
  const float* wk     = (const float*)d_in[8];
  const float* bk     = (const float*)d_in[9];
  const float* wv     = (const float*)d_in[10];
  const float* bv     = (const float*)d_in[11];
  const float* w_fin  = (const float*)d_in[12];
  const float* bn2_g  = (const float*)d_in[13];
  const float* bn2_b  = (const float*)d_in[14];
  const float* bn2_m  = (const float*)d_in[15];
  const float* bn2_v  = (const float*)d_in[16];
  const float* gamma  = (const float*)d_in[17];
  float* out = (float*)d_out;

  char* ws = (char*)d_ws;
  float*  x1p  = (float*)(ws);                       // 4,917,248 B
  ushort* xh   = (ushort*)(ws + 4917248);            // 2,459,648 B
  ushort* xl   = (ushort*)(ws + 7376896);            // 2,459,648 B
  ushort* qsp  = (ushort*)(ws + 9836544);            // 1,179,648 B
  ushort* ksp  = (ushort*)(ws + 11016192);           // 1,179,648 B
  ushort* vfr  = (ushort*)(ws + 12195840);           // 2,359,296 B
  ushort* fpre = (ushort*)(ws + 14555136);           //   147,456 B
  ushort* ffin = (ushort*)(ws + 14702592);           //   147,456 B -> end 14,850,048
  ushort* ofh = xh;   // xh/xl dead after conv1; reuse for attn output planes
  ushort* ofl = xl;

  // zero bf16 plane region (pad rings must be 0; interiors rewritten each call)
  hipMemsetAsync(ws + 4917248, 0, 4919296, stream);

  wprep<<<dim3(144, 2), 256, 0, stream>>>(w_pre, w_fin, fpre, ffin);
  pad_split<<<dim3(128), 256, 0, stream>>>(x, xh, xl);
  conv3x3_mfma<true><<<dim3(294, 2), 128, 0, stream>>>(
      xh, xl, fpre, bn1_g, bn1_b, bn1_m, bn1_v, x1p);
  qkv_kernel<<<dim3(576, 6, 2), 64, 0, stream>>>(
      x1p, wq, bq, wk, bk, wv, bv, qsp, ksp, vfr);
  attn_kernel<<<dim3(288, 2), 256, 0, stream>>>(
      qsp, ksp, vfr, x1p, gamma, ofh, ofl);
  conv3x3_mfma<false><<<dim3(294, 2), 128, 0, stream>>>(
      ofh, ofl, ffin, bn2_g, bn2_b, bn2_m, bn2_v, out);
}

// Round 17
// 162.164 us; speedup vs baseline: 1.0398x; 1.0323x over previous
//
#include <hip/hip_runtime.h>
#include <hip/hip_bf16.h>

// ---------------------------------------------------------------------------
// AttentionLayer round 16  ( = round 13 + batch-pinned XCDs + per-lane lsum )
//  - attn: 1D grid 576, b = id&1, qb = id>>1  -> consecutive block IDs
//    round-robin XCDs, so each XCD serves ONE batch; per-XCD L2 core set
//    drops 3.5MB (both batches) -> ~3MB (one) and K/V stay resident.
//    Pure block relabel of r13's kernel (no partials/seg-split).
//  - lsum kept per-lane (sum is linear); one pair-combine after the loop
//    replaces 72 per-tile permlane round-trips. m stays pair-consistent.
//  - rest = r13: QBLK=32, 4 waves, SW-pipelined QK, max3 tree, in-block merge.
//  - convs/qkv byte-identical to round 13/11/5.
// ---------------------------------------------------------------------------

using short8 = __attribute__((ext_vector_type(8))) short;   // 8 bf16
using f32x4  = __attribute__((ext_vector_type(4))) float;
using f32x16 = __attribute__((ext_vector_type(16))) float;
using u32x4  = __attribute__((ext_vector_type(4))) unsigned;
typedef unsigned u32;
typedef unsigned short ushort;

#define NPIX 9216
#define PW 98
#define PLANE 9604            // fp32 padded plane (98*98)
#define PLANEB 9608           // bf16 padded plane, padded to 8 for b128 align
#define SEG 240               // conv staged window
#define LOG2E 1.44269504088896340736f

__device__ __forceinline__ ushort f2bf(float f) {
  u32 x = __builtin_bit_cast(u32, f);
  return (ushort)((x + 0x7fffu + ((x >> 16) & 1u)) >> 16);
}
__device__ __forceinline__ float bf2f(ushort h) {
  return __builtin_bit_cast(float, (u32)h << 16);
}
__device__ __forceinline__ float max3f(float a, float b, float c) {
  float d;
  asm("v_max3_f32 %0, %1, %2, %3" : "=v"(d) : "v"(a), "v"(b), "v"(c));
  return d;
}

// ---------------- weight prep: OIHW fp32 -> frag-linear bf16 hi/lo ----------
__global__ __launch_bounds__(256) void wprep(
    const float* __restrict__ w_pre, const float* __restrict__ w_fin,
    ushort* __restrict__ fpre, ushort* __restrict__ ffin)
{
  const int i = blockIdx.x * 256 + threadIdx.x;    // [0, 36864)
  const float* w = blockIdx.y ? w_fin : w_pre;
  ushort* dst    = blockIdx.y ? ffin : fpre;
  const int kk = i & 7, l = (i >> 3) & 63, cot = (i >> 9) & 1;
  const int chunk = (i >> 10) & 3, tap = i >> 12;
  const int co = cot * 32 + (l & 31);
  const int ci = chunk * 16 + 8 * (l >> 5) + kk;
  const float wv = w[co * 576 + ci * 9 + tap];
  const ushort h = f2bf(wv);
  const ushort lo = f2bf(wv - bf2f(h));
  const int base = tap * 8192 + chunk * 2048 + cot * 1024 + l * 8 + kk;
  dst[base] = h;
  dst[base + 512] = lo;
}

// ---------------- pad+split: x fp32 [96x96] -> xh/xl bf16 [98x98] interior --
__global__ __launch_bounds__(256) void pad_split(
    const float* __restrict__ in, ushort* __restrict__ xh, ushort* __restrict__ xl)
{
  const int plane = blockIdx.x;   // 0..127
  const float* src = in + (size_t)plane * 9216;
  const size_t dbase = (size_t)plane * PLANEB;
  for (int idx = threadIdx.x; idx < 9216; idx += 256) {
    const int y = idx / 96, x = idx - y * 96;
    const float v = src[idx];
    const ushort h = f2bf(v);
    const size_t d = dbase + (y + 1) * PW + x + 1;
    xh[d] = h;
    xl[d] = f2bf(v - bf2f(h));
  }
}

// ---------------- conv3x3 + BN + ReLU via MFMA (split-bf16, 4 products) -----
template <bool PADOUT>
__global__ __launch_bounds__(128) void conv3x3_mfma(
    const ushort* __restrict__ xh, const ushort* __restrict__ xl,
    const ushort* __restrict__ wfrag,
    const float* __restrict__ gg, const float* __restrict__ bb_,
    const float* __restrict__ mm, const float* __restrict__ vv,
    float* __restrict__ outp)
{
  __shared__ ushort stage[2][SEG][18];   // [hl][e][ci], 36B rows (bank-clean)
  __shared__ float scb[64], shb[64];
  const int n0  = blockIdx.x * 32;
  const int b   = blockIdx.y;
  const int tid = threadIdx.x;
  const int wm  = tid >> 6;
  const int lane = tid & 63;
  const int li = lane & 31, hi = lane >> 5;

  if (tid < 64) {
    const float sc = gg[tid] * rsqrtf(vv[tid] + 1e-5f);
    scb[tid] = sc;
    shb[tid] = bb_[tid] - mm[tid] * sc;
  }

  f32x16 acc = {};
  const int sbase = n0 - 8;

  for (int chunk = 0; chunk < 4; ++chunk) {
    __syncthreads();
#pragma unroll
    for (int it = 0; it < 8; ++it) {
      const int item = tid + it * 128;
      if (item < 960) {
        const int pl   = item >= 480;
        const int rem  = pl ? item - 480 : item;
        const int eblk = rem >> 4;
        const int ci   = rem & 15;
        const ushort* src = (pl ? xl : xh) +
            (size_t)(b * 64 + chunk * 16 + ci) * PLANEB + sbase + eblk * 8;
        const short8 v = *(const short8*)src;
#pragma unroll
        for (int j = 0; j < 8; ++j) stage[pl][eblk * 8 + j][ci] = (ushort)v[j];
      }
    }
    __syncthreads();

    const ushort* wb0 = wfrag + (size_t)(chunk * 2048 + wm * 1024 + lane * 8);
    short8 ah = *(const short8*)(wb0);
    short8 al = *(const short8*)(wb0 + 512);
#pragma unroll
    for (int tap = 0; tap < 9; ++tap) {
      const int eoff = (tap / 3) * PW + (tap % 3) + 7 + li;
      const short8 bh = *(const short8*)&stage[0][eoff][hi * 8];
      const short8 bl = *(const short8*)&stage[1][eoff][hi * 8];
      short8 ahn, aln;
      if (tap < 8) {
        const ushort* wbn = wb0 + (size_t)(tap + 1) * 8192;
        ahn = *(const short8*)(wbn);
        aln = *(const short8*)(wbn + 512);
      }
      acc = __builtin_amdgcn_mfma_f32_32x32x16_bf16(ah, bh, acc, 0, 0, 0);
      acc = __builtin_amdgcn_mfma_f32_32x32x16_bf16(ah, bl, acc, 0, 0, 0);
      acc = __builtin_amdgcn_mfma_f32_32x32x16_bf16(al, bh, acc, 0, 0, 0);
      acc = __builtin_amdgcn_mfma_f32_32x32x16_bf16(al, bl, acc, 0, 0, 0);
      if (tap < 8) { ah = ahn; al = aln; }
    }
  }

  const int pix = n0 + li;
  const int y = pix / PW;
  const int x = pix - y * PW;
  if (x >= 1 && x <= 96) {
#pragma unroll
    for (int r = 0; r < 16; ++r) {
      const int co = wm * 32 + (r & 3) + 8 * (r >> 2) + 4 * hi;
      const float val = fmaxf(scb[co] * acc[r] + shb[co], 0.f);
      if (PADOUT)
        outp[(size_t)(b * 64 + co) * PLANE + pix + PW] = val;
      else
        outp[(size_t)(b * 64 + co) * 9216 + y * 96 + (x - 1)] = val;
    }
  }
}

// ---------------- 1x1 q/k/v as bf16 MFMA GEMM -------------------------------
// cot 0 = q (x LOG2E) -> qsp[N][32] (hi 0..15, lo 16..31); 1 = k -> ksp same;
// 2..5 = v channel-quarters -> vfrag fragment-linear.
__global__ __launch_bounds__(64) void qkv_kernel(
    const float* __restrict__ x1p,
    const float* __restrict__ wq, const float* __restrict__ bq,
    const float* __restrict__ wk, const float* __restrict__ bk,
    const float* __restrict__ wv, const float* __restrict__ bv,
    ushort* __restrict__ qsp, ushort* __restrict__ ksp,
    ushort* __restrict__ vfrag)
{
  const int pix0 = blockIdx.x * 16;
  const int cot  = blockIdx.y;
  const int b    = blockIdx.z;
  const int lane = threadIdx.x;
  const int g    = lane >> 4;
  const int col  = lane & 15;

  const float* wr;
  const float* bias;
  if (cot == 0)      { wr = wq + col * 64; bias = bq; }
  else if (cot == 1) { wr = wk + col * 64; bias = bk; }
  else               { wr = wv + ((cot - 2) * 16 + col) * 64; bias = bv + (cot - 2) * 16; }

  const int yy = pix0 / 96, xx = pix0 - yy * 96;
  const int ro = (yy + 1) * PW + xx + 1;

  f32x4 acc = (f32x4){0.f, 0.f, 0.f, 0.f};
  const float* xb = x1p + (size_t)b * 64 * PLANE;
#pragma unroll
  for (int kt = 0; kt < 2; ++kt) {
    const float4 wa = *(const float4*)(wr + kt * 32 + 8 * g);
    const float4 wb2 = *(const float4*)(wr + kt * 32 + 8 * g + 4);
    short8 af;
    af[0] = (short)f2bf(wa.x); af[1] = (short)f2bf(wa.y);
    af[2] = (short)f2bf(wa.z); af[3] = (short)f2bf(wa.w);
    af[4] = (short)f2bf(wb2.x); af[5] = (short)f2bf(wb2.y);
    af[6] = (short)f2bf(wb2.z); af[7] = (short)f2bf(wb2.w);
    short8 bf;
#pragma unroll
    for (int jj = 0; jj < 8; ++jj)
      bf[jj] = (short)f2bf(xb[(size_t)(kt * 32 + 8 * g + jj) * PLANE + ro + col]);
    acc = __builtin_amdgcn_mfma_f32_16x16x32_bf16(af, bf, acc, 0, 0, 0);
  }
  if (cot < 2) {
    ushort* dst = (cot == 0 ? qsp : ksp) + ((size_t)(b * NPIX + pix0 + col)) * 32;
    const float scl = (cot == 0) ? LOG2E : 1.f;
#pragma unroll
    for (int r = 0; r < 4; ++r) {
      const int cl = 4 * g + r;
      const float val = (acc[r] + bias[cl]) * scl;
      const ushort h = f2bf(val);
      dst[cl] = h;
      dst[16 + cl] = f2bf(val - bf2f(h));
    }
  } else {
    ushort* dst = vfrag + (size_t)b * 589824;
    const int pix = pix0 + col;
    const int jt = pix >> 5, ks = (pix >> 4) & 1;
    const int lhalf = 32 * ((pix >> 3) & 1);
    const int kk = pix & 7;
#pragma unroll
    for (int r = 0; r < 4; ++r) {
      const int cl = 4 * g + r;
      const int c = (cot - 2) * 16 + cl;
      const int h = c >> 5;
      const int lA = (c & 31) + lhalf;
      dst[(size_t)((((jt * 2 + h) * 2 + ks) * 64 + lA)) * 8 + kk] =
          f2bf(acc[r] + bias[cl]);
    }
  }
}

// ---------------- flash attention, QBLK=32, 4-wave j-split, SW-pipelined ----
// 1D grid 576: b = id&1, qb = id>>1 -> each XCD serves one batch (L2 pinning).
// Wave w: j in [w*2304, (w+1)*2304), 72 tiles of 32. lsum kept per-lane;
// pair-combined once after the loop (m is pair-consistent via the pm swap).
__global__ __launch_bounds__(256, 3) void attn_kernel(
    const ushort* __restrict__ qsp, const ushort* __restrict__ ksp,
    const ushort* __restrict__ vfrag, const float* __restrict__ x1p,
    const float* __restrict__ gamma_p,
    ushort* __restrict__ ofh, ushort* __restrict__ ofl)
{
  __shared__ float2 mlb[4][32];
  __shared__ float obuf[32][65];
  __shared__ float lbuf[32];

  const int id  = blockIdx.x;
  const int b   = id & 1;
  const int i0  = (id >> 1) * 32;
  const int tid = threadIdx.x;
  const int w   = tid >> 6;
  const int lane = tid & 63;
  const int li  = lane & 31;
  const int hi  = lane >> 5;

  for (int idx = tid; idx < 32 * 65; idx += 256) ((float*)obuf)[idx] = 0.f;
  if (tid < 32) lbuf[tid] = 0.f;
  __syncthreads();

  const ushort* kb    = ksp + (size_t)b * NPIX * 32;
  const ushort* vbase = vfrag + (size_t)b * 589824;

  const ushort* qrow = qsp + ((size_t)b * NPIX + i0 + li) * 32 + 8 * hi;
  const short8 qfh = *(const short8*)(qrow);
  const short8 qfl = *(const short8*)(qrow + 16);

  float m = -INFINITY;
  float lsum = 0.f;          // per-lane partial; pair-combined after the loop
  f32x16 acc[2] = {};

  const int jt0 = w * 72;
  const ushort* kptr = kb + (size_t)(jt0 * 32 + li) * 32 + 8 * hi;
  const ushort* vptr = vbase + ((size_t)(jt0 * 4) * 64 + lane) * 8;

  const f32x16 zf = {};

  // ---- prologue: s for tile 0; K(1) in regs; V(0) in regs ----
  short8 kh0 = *(const short8*)kptr;
  short8 kl0 = *(const short8*)(kptr + 16);
  f32x16 s = __builtin_amdgcn_mfma_f32_32x32x16_bf16(kh0, qfh, zf, 0, 0, 0);
  s = __builtin_amdgcn_mfma_f32_32x32x16_bf16(kl0, qfh, s, 0, 0, 0);
  s = __builtin_amdgcn_mfma_f32_32x32x16_bf16(kh0, qfl, s, 0, 0, 0);
  kptr += 1024;
  short8 kh_n = *(const short8*)kptr;        // K(1)
  short8 kl_n = *(const short8*)(kptr + 16);
  short8 vf00 = *(const short8*)(vptr);
  short8 vf01 = *(const short8*)(vptr + 512);
  short8 vf10 = *(const short8*)(vptr + 1024);
  short8 vf11 = *(const short8*)(vptr + 1536);

  for (int t = 0; t < 72; ++t) {
    // QK for tile t+1 issued NOW; retires under softmax(t)'s VALU work
    f32x16 s_next;
    if (t < 71) {
      s_next = __builtin_amdgcn_mfma_f32_32x32x16_bf16(kh_n, qfh, zf, 0, 0, 0);
      s_next = __builtin_amdgcn_mfma_f32_32x32x16_bf16(kl_n, qfh, s_next, 0, 0, 0);
      s_next = __builtin_amdgcn_mfma_f32_32x32x16_bf16(kh_n, qfl, s_next, 0, 0, 0);
    }

    // prefetch K(t+2), V(t+1)
    short8 kh_p, kl_p, v00n, v01n, v10n, v11n;
    if (t < 70) {
      kptr += 1024;
      kh_p = *(const short8*)kptr;
      kl_p = *(const short8*)(kptr + 16);
    }
    if (t < 71) {
      vptr += 2048;
      v00n = *(const short8*)(vptr);
      v01n = *(const short8*)(vptr + 512);
      v10n = *(const short8*)(vptr + 1024);
      v11n = *(const short8*)(vptr + 1536);
    }

    // ---- softmax on s (tile t) ----
    float pm, q1, q2, q3, q4;
    pm = max3f(s[0], s[1], s[2]);
    q1 = max3f(s[3], s[4], s[5]);
    q2 = max3f(s[6], s[7], s[8]);
    q3 = max3f(s[9], s[10], s[11]);
    q4 = max3f(s[12], s[13], s[14]);
    pm = max3f(pm, q1, q2);
    pm = max3f(pm, q3, q4);
    pm = fmaxf(pm, s[15]);
    {
      float o = pm;
      asm("v_permlane32_swap_b32 %0, %1" : "+v"(o), "+v"(pm));
      pm = fmaxf(pm, o);
    }

    if (__any(pm > m + 8.f)) {   // defer-max rescale (T13)
      const float mnew = fmaxf(m, pm);
      const float corr = __builtin_amdgcn_exp2f(m - mnew);
      lsum *= corr;
      acc[0] *= corr;
      acc[1] *= corr;
      m = mnew;
    }

#pragma unroll
    for (int r = 0; r < 16; ++r) s[r] = __builtin_amdgcn_exp2f(s[r] - m);
    lsum += (((s[0] + s[1]) + (s[2] + s[3])) + ((s[4] + s[5]) + (s[6] + s[7]))) +
            (((s[8] + s[9]) + (s[10] + s[11])) + ((s[12] + s[13]) + (s[14] + s[15])));

    u32 c01, c23, c45, c67, d01, d23, d45, d67;
    asm("v_cvt_pk_bf16_f32 %0, %1, %2" : "=v"(c01) : "v"(s[0]),  "v"(s[1]));
    asm("v_cvt_pk_bf16_f32 %0, %1, %2" : "=v"(c23) : "v"(s[2]),  "v"(s[3]));
    asm("v_cvt_pk_bf16_f32 %0, %1, %2" : "=v"(c45) : "v"(s[4]),  "v"(s[5]));
    asm("v_cvt_pk_bf16_f32 %0, %1, %2" : "=v"(c67) : "v"(s[6]),  "v"(s[7]));
    asm("v_cvt_pk_bf16_f32 %0, %1, %2" : "=v"(d01) : "v"(s[8]),  "v"(s[9]));
    asm("v_cvt_pk_bf16_f32 %0, %1, %2" : "=v"(d23) : "v"(s[10]), "v"(s[11]));
    asm("v_cvt_pk_bf16_f32 %0, %1, %2" : "=v"(d45) : "v"(s[12]), "v"(s[13]));
    asm("v_cvt_pk_bf16_f32 %0, %1, %2" : "=v"(d67) : "v"(s[14]), "v"(s[15]));
    asm("v_permlane32_swap_b32 %0, %1" : "+v"(c45), "+v"(c01));
    asm("v_permlane32_swap_b32 %0, %1" : "+v"(c67), "+v"(c23));
    asm("v_permlane32_swap_b32 %0, %1" : "+v"(d45), "+v"(d01));
    asm("v_permlane32_swap_b32 %0, %1" : "+v"(d67), "+v"(d23));
    const short8 pf1 = __builtin_bit_cast(short8, (u32x4){c01, c23, c45, c67});
    const short8 pf2 = __builtin_bit_cast(short8, (u32x4){d01, d23, d45, d67});

    acc[0] = __builtin_amdgcn_mfma_f32_32x32x16_bf16(vf00, pf1, acc[0], 0, 0, 0);
    acc[0] = __builtin_amdgcn_mfma_f32_32x32x16_bf16(vf01, pf2, acc[0], 0, 0, 0);
    acc[1] = __builtin_amdgcn_mfma_f32_32x32x16_bf16(vf10, pf1, acc[1], 0, 0, 0);
    acc[1] = __builtin_amdgcn_mfma_f32_32x32x16_bf16(vf11, pf2, acc[1], 0, 0, 0);

    // rotate pipeline state
    if (t < 71) {
      s = s_next;
      vf00 = v00n; vf01 = v01n; vf10 = v10n; vf11 = v11n;
    }
    if (t < 70) { kh_n = kh_p; kl_n = kl_p; }
  }

  // pair-combine lsum (m identical across the lane pair)
  {
    float o = lsum;
    asm("v_permlane32_swap_b32 %0, %1" : "+v"(o), "+v"(lsum));
    lsum = lsum + o;
  }

  // ---- merge 4 waves ----
  if (hi == 0) { float2 t2; t2.x = m; t2.y = lsum; mlb[w][li] = t2; }
  __syncthreads();
  float M = -INFINITY;
#pragma unroll
  for (int ww = 0; ww < 4; ++ww) M = fmaxf(M, mlb[ww][li].x);
  const float f = __builtin_amdgcn_exp2f(m - M);
  if (hi == 0) atomicAdd(&lbuf[li], lsum * f);
#pragma unroll
  for (int hh = 0; hh < 2; ++hh)
#pragma unroll
    for (int r = 0; r < 16; ++r) {
      const int c = (r & 3) + 8 * (r >> 2) + 4 * hi + 32 * hh;
      atomicAdd(&obuf[li][c], acc[hh][r] * f);
    }
  __syncthreads();

  const float gm = gamma_p[0];
  for (int idx = tid; idx < 2048; idx += 256) {
    const int il = idx & 31, c = idx >> 5;
    const int p = i0 + il;
    const int y = p / 96, x = p - y * 96;
    const int ro = (y + 1) * PW + x + 1;
    const float val = obuf[il][c] / lbuf[il] * gm +
                      x1p[(size_t)(b * 64 + c) * PLANE + ro];
    const ushort h = f2bf(val);
    const size_t d = (size_t)(b * 64 + c) * PLANEB + ro;
    ofh[d] = h;
    ofl[d] = f2bf(val - bf2f(h));
  }
}

// ---------------------------------------------------------------------------
extern "C" void kernel_launch(void* const* d_in, const int* in_sizes, int n_in,
                              void* d_out, int out_size, void* d_ws, size_t ws_size,
                              hipStream_t stream) {
  const float* x      = (const float*)d_in[0];
  const float* w_pre  = (const float*)d_in[1];
  const float* bn1_g  = (const float*)d_in[2];
  const float* bn1_b  = (const float*)d_in[3];
  const float* bn1_m  = (const float*)d_in[4];
  const float* bn1_v  = (const float*)d_in[5];
  const float* wq     = (const float*)d_in[6];
  const float* bq     = (const float*)d_in[7];
  const float* wk     = (const float*)d_in[8];
  const float* bk     = (const float*)d_in[9];
  const float* wv     = (const float*)d_in[10];
  const float* bv     = (const float*)d_in[11];
  const float* w_fin  = (const float*)d_in[12];
  const float* bn2_g  = (const float*)d_in[13];
  const float* bn2_b  = (const float*)d_in[14];
  const float* bn2_m  = (const float*)d_in[15];
  const float* bn2_v  = (const float*)d_in[16];
  const float* gamma  = (const float*)d_in[17];
  float* out = (float*)d_out;

  char* ws = (char*)d_ws;
  float*  x1p  = (float*)(ws);                       // 4,917,248 B
  ushort* xh   = (ushort*)(ws + 4917248);            // 2,459,648 B
  ushort* xl   = (ushort*)(ws + 7376896);            // 2,459,648 B
  ushort* qsp  = (ushort*)(ws + 9836544);            // 1,179,648 B
  ushort* ksp  = (ushort*)(ws + 11016192);           // 1,179,648 B
  ushort* vfr  = (ushort*)(ws + 12195840);           // 2,359,296 B
  ushort* fpre = (ushort*)(ws + 14555136);           //   147,456 B
  ushort* ffin = (ushort*)(ws + 14702592);           //   147,456 B -> end 14,850,048
  ushort* ofh = xh;   // xh/xl dead after conv1; reuse for attn output planes
  ushort* ofl = xl;

  // zero bf16 plane region (pad rings must be 0; interiors rewritten each call)
  hipMemsetAsync(ws + 4917248, 0, 4919296, stream);

  wprep<<<dim3(144, 2), 256, 0, stream>>>(w_pre, w_fin, fpre, ffin);
  pad_split<<<dim3(128), 256, 0, stream>>>(x, xh, xl);
  conv3x3_mfma<true><<<dim3(294, 2), 128, 0, stream>>>(
      xh, xl, fpre, bn1_g, bn1_b, bn1_m, bn1_v, x1p);
  qkv_kernel<<<dim3(576, 6, 2), 64, 0, stream>>>(
      x1p, wq, bq, wk, bk, wv, bv, qsp, ksp, vfr);
  attn_kernel<<<dim3(576), 256, 0, stream>>>(
      qsp, ksp, vfr, x1p, gamma, ofh, ofl);
  conv3x3_mfma<false><<<dim3(294, 2), 128, 0, stream>>>(
      ofh, ofl, ffin, bn2_g, bn2_b, bn2_m, bn2_v, out);
}

// Round 18
// 156.936 us; speedup vs baseline: 1.0745x; 1.0333x over previous
//
#include <hip/hip_runtime.h>
#include <hip/hip_bf16.h>

// ---------------------------------------------------------------------------
// AttentionLayer round 17  ( = round 16 + conv 64-pix tile + attn setprio )
//  - conv3x3: 64-pixel block tile (4 waves: co-half x pix-half), halo window
//    staged once for 64 pixels (was 32) -> ~44% less staging work/barriers.
//  - attn: s_setprio(1) around QK-prefetch + PV MFMA clusters (T5).
//  - rest byte-identical to round 16 (batch-pinned 1D grid, SW-pipelined QK,
//    per-lane lsum, split-QK energies, frag-linear V).
// ---------------------------------------------------------------------------

using short8 = __attribute__((ext_vector_type(8))) short;   // 8 bf16
using f32x4  = __attribute__((ext_vector_type(4))) float;
using f32x16 = __attribute__((ext_vector_type(16))) float;
using u32x4  = __attribute__((ext_vector_type(4))) unsigned;
typedef unsigned u32;
typedef unsigned short ushort;

#define NPIX 9216
#define PW 98
#define PLANE 9604            // fp32 padded plane (98*98)
#define PLANEB 9608           // bf16 padded plane, padded to 8 for b128 align
#define SEG2 272              // conv staged window for 64-pix tile (8+64+197->272)
#define LOG2E 1.44269504088896340736f

__device__ __forceinline__ ushort f2bf(float f) {
  u32 x = __builtin_bit_cast(u32, f);
  return (ushort)((x + 0x7fffu + ((x >> 16) & 1u)) >> 16);
}
__device__ __forceinline__ float bf2f(ushort h) {
  return __builtin_bit_cast(float, (u32)h << 16);
}
__device__ __forceinline__ float max3f(float a, float b, float c) {
  float d;
  asm("v_max3_f32 %0, %1, %2, %3" : "=v"(d) : "v"(a), "v"(b), "v"(c));
  return d;
}

// ---------------- weight prep: OIHW fp32 -> frag-linear bf16 hi/lo ----------
__global__ __launch_bounds__(256) void wprep(
    const float* __restrict__ w_pre, const float* __restrict__ w_fin,
    ushort* __restrict__ fpre, ushort* __restrict__ ffin)
{
  const int i = blockIdx.x * 256 + threadIdx.x;    // [0, 36864)
  const float* w = blockIdx.y ? w_fin : w_pre;
  ushort* dst    = blockIdx.y ? ffin : fpre;
  const int kk = i & 7, l = (i >> 3) & 63, cot = (i >> 9) & 1;
  const int chunk = (i >> 10) & 3, tap = i >> 12;
  const int co = cot * 32 + (l & 31);
  const int ci = chunk * 16 + 8 * (l >> 5) + kk;
  const float wv = w[co * 576 + ci * 9 + tap];
  const ushort h = f2bf(wv);
  const ushort lo = f2bf(wv - bf2f(h));
  const int base = tap * 8192 + chunk * 2048 + cot * 1024 + l * 8 + kk;
  dst[base] = h;
  dst[base + 512] = lo;
}

// ---------------- pad+split: x fp32 [96x96] -> xh/xl bf16 [98x98] interior --
__global__ __launch_bounds__(256) void pad_split(
    const float* __restrict__ in, ushort* __restrict__ xh, ushort* __restrict__ xl)
{
  const int plane = blockIdx.x;   // 0..127
  const float* src = in + (size_t)plane * 9216;
  const size_t dbase = (size_t)plane * PLANEB;
  for (int idx = threadIdx.x; idx < 9216; idx += 256) {
    const int y = idx / 96, x = idx - y * 96;
    const float v = src[idx];
    const ushort h = f2bf(v);
    const size_t d = dbase + (y + 1) * PW + x + 1;
    xh[d] = h;
    xl[d] = f2bf(v - bf2f(h));
  }
}

// ---------------- conv3x3 + BN + ReLU via MFMA, 64-pix tile -----------------
// grid (147, 2), block 256 = 4 waves: wm&1 = co-half, wm>>1 = pixel-half.
template <bool PADOUT>
__global__ __launch_bounds__(256) void conv3x3_mfma(
    const ushort* __restrict__ xh, const ushort* __restrict__ xl,
    const ushort* __restrict__ wfrag,
    const float* __restrict__ gg, const float* __restrict__ bb_,
    const float* __restrict__ mm, const float* __restrict__ vv,
    float* __restrict__ outp)
{
  __shared__ ushort stage[2][SEG2][18];   // [hl][e][ci], 36B rows (bank-clean)
  __shared__ float scb[64], shb[64];
  const int n0  = blockIdx.x * 64;
  const int b   = blockIdx.y;
  const int tid = threadIdx.x;
  const int wm  = tid >> 6;          // 0..3
  const int coh = wm & 1;
  const int ph  = wm >> 1;
  const int lane = tid & 63;
  const int li = lane & 31, hi = lane >> 5;

  if (tid < 64) {
    const float sc = gg[tid] * rsqrtf(vv[tid] + 1e-5f);
    scb[tid] = sc;
    shb[tid] = bb_[tid] - mm[tid] * sc;
  }

  f32x16 acc = {};
  const int sbase = n0 - 8;

  for (int chunk = 0; chunk < 4; ++chunk) {
    __syncthreads();
    // stage 2 planes x 16 ci x 272 e ; 1088 b128 items, ci-fast
#pragma unroll
    for (int it = 0; it < 5; ++it) {
      const int item = tid + it * 256;
      if (item < 1088) {
        const int pl   = item >= 544;
        const int rem  = pl ? item - 544 : item;
        const int eblk = rem >> 4;      // 0..33
        const int ci   = rem & 15;
        const ushort* src = (pl ? xl : xh) +
            (size_t)(b * 64 + chunk * 16 + ci) * PLANEB + sbase + eblk * 8;
        const short8 v = *(const short8*)src;
#pragma unroll
        for (int j = 0; j < 8; ++j) stage[pl][eblk * 8 + j][ci] = (ushort)v[j];
      }
    }
    __syncthreads();

    const ushort* wb0 = wfrag + (size_t)(chunk * 2048 + coh * 1024 + lane * 8);
    short8 ah = *(const short8*)(wb0);
    short8 al = *(const short8*)(wb0 + 512);
#pragma unroll
    for (int tap = 0; tap < 9; ++tap) {
      const int eoff = (tap / 3) * PW + (tap % 3) + 7 + ph * 32 + li;
      const short8 bh = *(const short8*)&stage[0][eoff][hi * 8];
      const short8 bl = *(const short8*)&stage[1][eoff][hi * 8];
      short8 ahn, aln;
      if (tap < 8) {
        const ushort* wbn = wb0 + (size_t)(tap + 1) * 8192;
        ahn = *(const short8*)(wbn);
        aln = *(const short8*)(wbn + 512);
      }
      acc = __builtin_amdgcn_mfma_f32_32x32x16_bf16(ah, bh, acc, 0, 0, 0);
      acc = __builtin_amdgcn_mfma_f32_32x32x16_bf16(ah, bl, acc, 0, 0, 0);
      acc = __builtin_amdgcn_mfma_f32_32x32x16_bf16(al, bh, acc, 0, 0, 0);
      acc = __builtin_amdgcn_mfma_f32_32x32x16_bf16(al, bl, acc, 0, 0, 0);
      if (tap < 8) { ah = ahn; al = aln; }
    }
  }

  const int pix = n0 + ph * 32 + li;
  const int y = pix / PW;
  const int x = pix - y * PW;
  if (x >= 1 && x <= 96) {
#pragma unroll
    for (int r = 0; r < 16; ++r) {
      const int co = coh * 32 + (r & 3) + 8 * (r >> 2) + 4 * hi;
      const float val = fmaxf(scb[co] * acc[r] + shb[co], 0.f);
      if (PADOUT)
        outp[(size_t)(b * 64 + co) * PLANE + pix + PW] = val;
      else
        outp[(size_t)(b * 64 + co) * 9216 + y * 96 + (x - 1)] = val;
    }
  }
}

// ---------------- 1x1 q/k/v as bf16 MFMA GEMM -------------------------------
__global__ __launch_bounds__(64) void qkv_kernel(
    const float* __restrict__ x1p,
    const float* __restrict__ wq, const float* __restrict__ bq,
    const float* __restrict__ wk, const float* __restrict__ bk,
    const float* __restrict__ wv, const float* __restrict__ bv,
    ushort* __restrict__ qsp, ushort* __restrict__ ksp,
    ushort* __restrict__ vfrag)
{
  const int pix0 = blockIdx.x * 16;
  const int cot  = blockIdx.y;
  const int b    = blockIdx.z;
  const int lane = threadIdx.x;
  const int g    = lane >> 4;
  const int col  = lane & 15;

  const float* wr;
  const float* bias;
  if (cot == 0)      { wr = wq + col * 64; bias = bq; }
  else if (cot == 1) { wr = wk + col * 64; bias = bk; }
  else               { wr = wv + ((cot - 2) * 16 + col) * 64; bias = bv + (cot - 2) * 16; }

  const int yy = pix0 / 96, xx = pix0 - yy * 96;
  const int ro = (yy + 1) * PW + xx + 1;

  f32x4 acc = (f32x4){0.f, 0.f, 0.f, 0.f};
  const float* xb = x1p + (size_t)b * 64 * PLANE;
#pragma unroll
  for (int kt = 0; kt < 2; ++kt) {
    const float4 wa = *(const float4*)(wr + kt * 32 + 8 * g);
    const float4 wb2 = *(const float4*)(wr + kt * 32 + 8 * g + 4);
    short8 af;
    af[0] = (short)f2bf(wa.x); af[1] = (short)f2bf(wa.y);
    af[2] = (short)f2bf(wa.z); af[3] = (short)f2bf(wa.w);
    af[4] = (short)f2bf(wb2.x); af[5] = (short)f2bf(wb2.y);
    af[6] = (short)f2bf(wb2.z); af[7] = (short)f2bf(wb2.w);
    short8 bf;
#pragma unroll
    for (int jj = 0; jj < 8; ++jj)
      bf[jj] = (short)f2bf(xb[(size_t)(kt * 32 + 8 * g + jj) * PLANE + ro + col]);
    acc = __builtin_amdgcn_mfma_f32_16x16x32_bf16(af, bf, acc, 0, 0, 0);
  }
  if (cot < 2) {
    ushort* dst = (cot == 0 ? qsp : ksp) + ((size_t)(b * NPIX + pix0 + col)) * 32;
    const float scl = (cot == 0) ? LOG2E : 1.f;
#pragma unroll
    for (int r = 0; r < 4; ++r) {
      const int cl = 4 * g + r;
      const float val = (acc[r] + bias[cl]) * scl;
      const ushort h = f2bf(val);
      dst[cl] = h;
      dst[16 + cl] = f2bf(val - bf2f(h));
    }
  } else {
    ushort* dst = vfrag + (size_t)b * 589824;
    const int pix = pix0 + col;
    const int jt = pix >> 5, ks = (pix >> 4) & 1;
    const int lhalf = 32 * ((pix >> 3) & 1);
    const int kk = pix & 7;
#pragma unroll
    for (int r = 0; r < 4; ++r) {
      const int cl = 4 * g + r;
      const int c = (cot - 2) * 16 + cl;
      const int h = c >> 5;
      const int lA = (c & 31) + lhalf;
      dst[(size_t)((((jt * 2 + h) * 2 + ks) * 64 + lA)) * 8 + kk] =
          f2bf(acc[r] + bias[cl]);
    }
  }
}

// ---------------- flash attention, QBLK=32, 4-wave j-split, SW-pipelined ----
// 1D grid 576: b = id&1, qb = id>>1 (batch-pinned XCD L2). setprio around MFMA.
__global__ __launch_bounds__(256, 3) void attn_kernel(
    const ushort* __restrict__ qsp, const ushort* __restrict__ ksp,
    const ushort* __restrict__ vfrag, const float* __restrict__ x1p,
    const float* __restrict__ gamma_p,
    ushort* __restrict__ ofh, ushort* __restrict__ ofl)
{
  __shared__ float2 mlb[4][32];
  __shared__ float obuf[32][65];
  __shared__ float lbuf[32];

  const int id  = blockIdx.x;
  const int b   = id & 1;
  const int i0  = (id >> 1) * 32;
  const int tid = threadIdx.x;
  const int w   = tid >> 6;
  const int lane = tid & 63;
  const int li  = lane & 31;
  const int hi  = lane >> 5;

  for (int idx = tid; idx < 32 * 65; idx += 256) ((float*)obuf)[idx] = 0.f;
  if (tid < 32) lbuf[tid] = 0.f;
  __syncthreads();

  const ushort* kb    = ksp + (size_t)b * NPIX * 32;
  const ushort* vbase = vfrag + (size_t)b * 589824;

  const ushort* qrow = qsp + ((size_t)b * NPIX + i0 + li) * 32 + 8 * hi;
  const short8 qfh = *(const short8*)(qrow);
  const short8 qfl = *(const short8*)(qrow + 16);

  float m = -INFINITY;
  float lsum = 0.f;
  f32x16 acc[2] = {};

  const int jt0 = w * 72;
  const ushort* kptr = kb + (size_t)(jt0 * 32 + li) * 32 + 8 * hi;
  const ushort* vptr = vbase + ((size_t)(jt0 * 4) * 64 + lane) * 8;

  const f32x16 zf = {};

  // ---- prologue ----
  short8 kh0 = *(const short8*)kptr;
  short8 kl0 = *(const short8*)(kptr + 16);
  f32x16 s = __builtin_amdgcn_mfma_f32_32x32x16_bf16(kh0, qfh, zf, 0, 0, 0);
  s = __builtin_amdgcn_mfma_f32_32x32x16_bf16(kl0, qfh, s, 0, 0, 0);
  s = __builtin_amdgcn_mfma_f32_32x32x16_bf16(kh0, qfl, s, 0, 0, 0);
  kptr += 1024;
  short8 kh_n = *(const short8*)kptr;
  short8 kl_n = *(const short8*)(kptr + 16);
  short8 vf00 = *(const short8*)(vptr);
  short8 vf01 = *(const short8*)(vptr + 512);
  short8 vf10 = *(const short8*)(vptr + 1024);
  short8 vf11 = *(const short8*)(vptr + 1536);

  for (int t = 0; t < 72; ++t) {
    // QK(t+1) under softmax(t)
    f32x16 s_next;
    if (t < 71) {
      __builtin_amdgcn_s_setprio(1);
      s_next = __builtin_amdgcn_mfma_f32_32x32x16_bf16(kh_n, qfh, zf, 0, 0, 0);
      s_next = __builtin_amdgcn_mfma_f32_32x32x16_bf16(kl_n, qfh, s_next, 0, 0, 0);
      s_next = __builtin_amdgcn_mfma_f32_32x32x16_bf16(kh_n, qfl, s_next, 0, 0, 0);
      __builtin_amdgcn_s_setprio(0);
    }

    short8 kh_p, kl_p, v00n, v01n, v10n, v11n;
    if (t < 70) {
      kptr += 1024;
      kh_p = *(const short8*)kptr;
      kl_p = *(const short8*)(kptr + 16);
    }
    if (t < 71) {
      vptr += 2048;
      v00n = *(const short8*)(vptr);
      v01n = *(const short8*)(vptr + 512);
      v10n = *(const short8*)(vptr + 1024);
      v11n = *(const short8*)(vptr + 1536);
    }

    // ---- softmax on s (tile t) ----
    float pm, q1, q2, q3, q4;
    pm = max3f(s[0], s[1], s[2]);
    q1 = max3f(s[3], s[4], s[5]);
    q2 = max3f(s[6], s[7], s[8]);
    q3 = max3f(s[9], s[10], s[11]);
    q4 = max3f(s[12], s[13], s[14]);
    pm = max3f(pm, q1, q2);
    pm = max3f(pm, q3, q4);
    pm = fmaxf(pm, s[15]);
    {
      float o = pm;
      asm("v_permlane32_swap_b32 %0, %1" : "+v"(o), "+v"(pm));
      pm = fmaxf(pm, o);
    }

    if (__any(pm > m + 8.f)) {   // defer-max rescale (T13)
      const float mnew = fmaxf(m, pm);
      const float corr = __builtin_amdgcn_exp2f(m - mnew);
      lsum *= corr;
      acc[0] *= corr;
      acc[1] *= corr;
      m = mnew;
    }

#pragma unroll
    for (int r = 0; r < 16; ++r) s[r] = __builtin_amdgcn_exp2f(s[r] - m);
    lsum += (((s[0] + s[1]) + (s[2] + s[3])) + ((s[4] + s[5]) + (s[6] + s[7]))) +
            (((s[8] + s[9]) + (s[10] + s[11])) + ((s[12] + s[13]) + (s[14] + s[15])));

    u32 c01, c23, c45, c67, d01, d23, d45, d67;
    asm("v_cvt_pk_bf16_f32 %0, %1, %2" : "=v"(c01) : "v"(s[0]),  "v"(s[1]));
    asm("v_cvt_pk_bf16_f32 %0, %1, %2" : "=v"(c23) : "v"(s[2]),  "v"(s[3]));
    asm("v_cvt_pk_bf16_f32 %0, %1, %2" : "=v"(c45) : "v"(s[4]),  "v"(s[5]));
    asm("v_cvt_pk_bf16_f32 %0, %1, %2" : "=v"(c67) : "v"(s[6]),  "v"(s[7]));
    asm("v_cvt_pk_bf16_f32 %0, %1, %2" : "=v"(d01) : "v"(s[8]),  "v"(s[9]));
    asm("v_cvt_pk_bf16_f32 %0, %1, %2" : "=v"(d23) : "v"(s[10]), "v"(s[11]));
    asm("v_cvt_pk_bf16_f32 %0, %1, %2" : "=v"(d45) : "v"(s[12]), "v"(s[13]));
    asm("v_cvt_pk_bf16_f32 %0, %1, %2" : "=v"(d67) : "v"(s[14]), "v"(s[15]));
    asm("v_permlane32_swap_b32 %0, %1" : "+v"(c45), "+v"(c01));
    asm("v_permlane32_swap_b32 %0, %1" : "+v"(c67), "+v"(c23));
    asm("v_permlane32_swap_b32 %0, %1" : "+v"(d45), "+v"(d01));
    asm("v_permlane32_swap_b32 %0, %1" : "+v"(d67), "+v"(d23));
    const short8 pf1 = __builtin_bit_cast(short8, (u32x4){c01, c23, c45, c67});
    const short8 pf2 = __builtin_bit_cast(short8, (u32x4){d01, d23, d45, d67});

    __builtin_amdgcn_s_setprio(1);
    acc[0] = __builtin_amdgcn_mfma_f32_32x32x16_bf16(vf00, pf1, acc[0], 0, 0, 0);
    acc[0] = __builtin_amdgcn_mfma_f32_32x32x16_bf16(vf01, pf2, acc[0], 0, 0, 0);
    acc[1] = __builtin_amdgcn_mfma_f32_32x32x16_bf16(vf10, pf1, acc[1], 0, 0, 0);
    acc[1] = __builtin_amdgcn_mfma_f32_32x32x16_bf16(vf11, pf2, acc[1], 0, 0, 0);
    __builtin_amdgcn_s_setprio(0);

    if (t < 71) {
      s = s_next;
      vf00 = v00n; vf01 = v01n; vf10 = v10n; vf11 = v11n;
    }
    if (t < 70) { kh_n = kh_p; kl_n = kl_p; }
  }

  // pair-combine lsum (m identical across the lane pair)
  {
    float o = lsum;
    asm("v_permlane32_swap_b32 %0, %1" : "+v"(o), "+v"(lsum));
    lsum = lsum + o;
  }

  // ---- merge 4 waves ----
  if (hi == 0) { float2 t2; t2.x = m; t2.y = lsum; mlb[w][li] = t2; }
  __syncthreads();
  float M = -INFINITY;
#pragma unroll
  for (int ww = 0; ww < 4; ++ww) M = fmaxf(M, mlb[ww][li].x);
  const float f = __builtin_amdgcn_exp2f(m - M);
  if (hi == 0) atomicAdd(&lbuf[li], lsum * f);
#pragma unroll
  for (int hh = 0; hh < 2; ++hh)
#pragma unroll
    for (int r = 0; r < 16; ++r) {
      const int c = (r & 3) + 8 * (r >> 2) + 4 * hi + 32 * hh;
      atomicAdd(&obuf[li][c], acc[hh][r] * f);
    }
  __syncthreads();

  const float gm = gamma_p[0];
  for (int idx = tid; idx < 2048; idx += 256) {
    const int il = idx & 31, c = idx >> 5;
    const int p = i0 + il;
    const int y = p / 96, x = p - y * 96;
    const int ro = (y + 1) * PW + x + 1;
    const float val = obuf[il][c] / lbuf[il] * gm +
                      x1p[(size_t)(b * 64 + c) * PLANE + ro];
    const ushort h = f2bf(val);
    const size_t d = (size_t)(b * 64 + c) * PLANEB + ro;
    ofh[d] = h;
    ofl[d] = f2bf(val - bf2f(h));
  }
}

// ---------------------------------------------------------------------------
extern "C" void kernel_launch(void* const* d_in, const int* in_sizes, int n_in,
                              void* d_out, int out_size, void* d_ws, size_t ws_size,
                              hipStream_t stream) {
  const float* x      = (const float*)d_in[0];
  const float* w_pre  = (const float*)d_in[1];
  const float* bn1_g  = (const float*)d_in[2];
  const float* bn1_b  = (const float*)d_in[3];
  const float* bn1_m  = (const float*)d_in[4];
  const float* bn1_v  = (const float*)d_in[5];
  const float* wq     = (const float*)d_in[6];
  const float* bq     = (const float*)d_in[7];
  const float* wk     = (const float*)d_in[8];
  const float* bk     = (const float*)d_in[9];
  const float* wv     = (const float*)d_in[10];
  const float* bv     = (const float*)d_in[11];
  const float* w_fin  = (const float*)d_in[12];
  const float* bn2_g  = (const float*)d_in[13];
  const float* bn2_b  = (const float*)d_in[14];
  const float* bn2_m  = (const float*)d_in[15];
  const float* bn2_v  = (const float*)d_in[16];
  const float* gamma  = (const float*)d_in[17];
  float* out = (float*)d_out;

  char* ws = (char*)d_ws;
  float*  x1p  = (float*)(ws);                       // 4,917,248 B
  ushort* xh   = (ushort*)(ws + 4917248);            // 2,459,648 B
  ushort* xl   = (ushort*)(ws + 7376896);            // 2,459,648 B
  ushort* qsp  = (ushort*)(ws + 9836544);            // 1,179,648 B
  ushort* ksp  = (ushort*)(ws + 11016192);           // 1,179,648 B
  ushort* vfr  = (ushort*)(ws + 12195840);           // 2,359,296 B
  ushort* fpre = (ushort*)(ws + 14555136);           //   147,456 B
  ushort* ffin = (ushort*)(ws + 14702592);           //   147,456 B -> end 14,850,048
  ushort* ofh = xh;   // xh/xl dead after conv1; reuse for attn output planes
  ushort* ofl = xl;

  // zero bf16 plane region (pad rings must be 0; interiors rewritten each call)
  hipMemsetAsync(ws + 4917248, 0, 4919296, stream);

  wprep<<<dim3(144, 2), 256, 0, stream>>>(w_pre, w_fin, fpre, ffin);
  pad_split<<<dim3(128), 256, 0, stream>>>(x, xh, xl);
  conv3x3_mfma<true><<<dim3(147, 2), 256, 0, stream>>>(
      xh, xl, fpre, bn1_g, bn1_b, bn1_m, bn1_v, x1p);
  qkv_kernel<<<dim3(576, 6, 2), 64, 0, stream>>>(
      x1p, wq, bq, wk, bk, wv, bv, qsp, ksp, vfr);
  attn_kernel<<<dim3(576), 256, 0, stream>>>(
      qsp, ksp, vfr, x1p, gamma, ofh, ofl);
  conv3x3_mfma<false><<<dim3(147, 2), 256, 0, stream>>>(
      ofh, ofl, ffin, bn2_g, bn2_b, bn2_m, bn2_v, out);
}

// Round 19
// 155.277 us; speedup vs baseline: 1.0860x; 1.0107x over previous
//
#include <hip/hip_runtime.h>
#include <hip/hip_bf16.h>

// ---------------------------------------------------------------------------
// AttentionLayer round 18  ( = round 17 − attn setprio (hurt 2.5us)
//                            + qkv merged: 6 cot-waves share one LDS x-tile )
//  - attn: exact round-16 kernel (batch-pinned 1D grid, SW-pipelined QK,
//    per-lane lsum; best measured 92.7us).
//  - qkv: grid (576,2), 384 threads (6 waves = q,k,v0..v3); x-tile staged
//    once (was re-read 6x with scattered scalar loads).
//  - conv3x3 64-pix tile, pad/wprep byte-identical to round 17.
// ---------------------------------------------------------------------------

using short8 = __attribute__((ext_vector_type(8))) short;   // 8 bf16
using f32x4  = __attribute__((ext_vector_type(4))) float;
using f32x16 = __attribute__((ext_vector_type(16))) float;
using u32x4  = __attribute__((ext_vector_type(4))) unsigned;
typedef unsigned u32;
typedef unsigned short ushort;

#define NPIX 9216
#define PW 98
#define PLANE 9604            // fp32 padded plane (98*98)
#define PLANEB 9608           // bf16 padded plane, padded to 8 for b128 align
#define SEG2 272              // conv staged window for 64-pix tile
#define LOG2E 1.44269504088896340736f

__device__ __forceinline__ ushort f2bf(float f) {
  u32 x = __builtin_bit_cast(u32, f);
  return (ushort)((x + 0x7fffu + ((x >> 16) & 1u)) >> 16);
}
__device__ __forceinline__ float bf2f(ushort h) {
  return __builtin_bit_cast(float, (u32)h << 16);
}
__device__ __forceinline__ float max3f(float a, float b, float c) {
  float d;
  asm("v_max3_f32 %0, %1, %2, %3" : "=v"(d) : "v"(a), "v"(b), "v"(c));
  return d;
}

// ---------------- weight prep: OIHW fp32 -> frag-linear bf16 hi/lo ----------
__global__ __launch_bounds__(256) void wprep(
    const float* __restrict__ w_pre, const float* __restrict__ w_fin,
    ushort* __restrict__ fpre, ushort* __restrict__ ffin)
{
  const int i = blockIdx.x * 256 + threadIdx.x;    // [0, 36864)
  const float* w = blockIdx.y ? w_fin : w_pre;
  ushort* dst    = blockIdx.y ? ffin : fpre;
  const int kk = i & 7, l = (i >> 3) & 63, cot = (i >> 9) & 1;
  const int chunk = (i >> 10) & 3, tap = i >> 12;
  const int co = cot * 32 + (l & 31);
  const int ci = chunk * 16 + 8 * (l >> 5) + kk;
  const float wv = w[co * 576 + ci * 9 + tap];
  const ushort h = f2bf(wv);
  const ushort lo = f2bf(wv - bf2f(h));
  const int base = tap * 8192 + chunk * 2048 + cot * 1024 + l * 8 + kk;
  dst[base] = h;
  dst[base + 512] = lo;
}

// ---------------- pad+split: x fp32 [96x96] -> xh/xl bf16 [98x98] interior --
__global__ __launch_bounds__(256) void pad_split(
    const float* __restrict__ in, ushort* __restrict__ xh, ushort* __restrict__ xl)
{
  const int plane = blockIdx.x;   // 0..127
  const float* src = in + (size_t)plane * 9216;
  const size_t dbase = (size_t)plane * PLANEB;
  for (int idx = threadIdx.x; idx < 9216; idx += 256) {
    const int y = idx / 96, x = idx - y * 96;
    const float v = src[idx];
    const ushort h = f2bf(v);
    const size_t d = dbase + (y + 1) * PW + x + 1;
    xh[d] = h;
    xl[d] = f2bf(v - bf2f(h));
  }
}

// ---------------- conv3x3 + BN + ReLU via MFMA, 64-pix tile -----------------
// grid (147, 2), block 256 = 4 waves: wm&1 = co-half, wm>>1 = pixel-half.
template <bool PADOUT>
__global__ __launch_bounds__(256) void conv3x3_mfma(
    const ushort* __restrict__ xh, const ushort* __restrict__ xl,
    const ushort* __restrict__ wfrag,
    const float* __restrict__ gg, const float* __restrict__ bb_,
    const float* __restrict__ mm, const float* __restrict__ vv,
    float* __restrict__ outp)
{
  __shared__ ushort stage[2][SEG2][18];   // [hl][e][ci], 36B rows (bank-clean)
  __shared__ float scb[64], shb[64];
  const int n0  = blockIdx.x * 64;
  const int b   = blockIdx.y;
  const int tid = threadIdx.x;
  const int wm  = tid >> 6;          // 0..3
  const int coh = wm & 1;
  const int ph  = wm >> 1;
  const int lane = tid & 63;
  const int li = lane & 31, hi = lane >> 5;

  if (tid < 64) {
    const float sc = gg[tid] * rsqrtf(vv[tid] + 1e-5f);
    scb[tid] = sc;
    shb[tid] = bb_[tid] - mm[tid] * sc;
  }

  f32x16 acc = {};
  const int sbase = n0 - 8;

  for (int chunk = 0; chunk < 4; ++chunk) {
    __syncthreads();
#pragma unroll
    for (int it = 0; it < 5; ++it) {
      const int item = tid + it * 256;
      if (item < 1088) {
        const int pl   = item >= 544;
        const int rem  = pl ? item - 544 : item;
        const int eblk = rem >> 4;      // 0..33
        const int ci   = rem & 15;
        const ushort* src = (pl ? xl : xh) +
            (size_t)(b * 64 + chunk * 16 + ci) * PLANEB + sbase + eblk * 8;
        const short8 v = *(const short8*)src;
#pragma unroll
        for (int j = 0; j < 8; ++j) stage[pl][eblk * 8 + j][ci] = (ushort)v[j];
      }
    }
    __syncthreads();

    const ushort* wb0 = wfrag + (size_t)(chunk * 2048 + coh * 1024 + lane * 8);
    short8 ah = *(const short8*)(wb0);
    short8 al = *(const short8*)(wb0 + 512);
#pragma unroll
    for (int tap = 0; tap < 9; ++tap) {
      const int eoff = (tap / 3) * PW + (tap % 3) + 7 + ph * 32 + li;
      const short8 bh = *(const short8*)&stage[0][eoff][hi * 8];
      const short8 bl = *(const short8*)&stage[1][eoff][hi * 8];
      short8 ahn, aln;
      if (tap < 8) {
        const ushort* wbn = wb0 + (size_t)(tap + 1) * 8192;
        ahn = *(const short8*)(wbn);
        aln = *(const short8*)(wbn + 512);
      }
      acc = __builtin_amdgcn_mfma_f32_32x32x16_bf16(ah, bh, acc, 0, 0, 0);
      acc = __builtin_amdgcn_mfma_f32_32x32x16_bf16(ah, bl, acc, 0, 0, 0);
      acc = __builtin_amdgcn_mfma_f32_32x32x16_bf16(al, bh, acc, 0, 0, 0);
      acc = __builtin_amdgcn_mfma_f32_32x32x16_bf16(al, bl, acc, 0, 0, 0);
      if (tap < 8) { ah = ahn; al = aln; }
    }
  }

  const int pix = n0 + ph * 32 + li;
  const int y = pix / PW;
  const int x = pix - y * PW;
  if (x >= 1 && x <= 96) {
#pragma unroll
    for (int r = 0; r < 16; ++r) {
      const int co = coh * 32 + (r & 3) + 8 * (r >> 2) + 4 * hi;
      const float val = fmaxf(scb[co] * acc[r] + shb[co], 0.f);
      if (PADOUT)
        outp[(size_t)(b * 64 + co) * PLANE + pix + PW] = val;
      else
        outp[(size_t)(b * 64 + co) * 9216 + y * 96 + (x - 1)] = val;
    }
  }
}

// ---------------- 1x1 q/k/v, 6 cot-waves share one LDS x-tile ---------------
// grid (576, 2), block 384 (6 waves): wave 0 = q, 1 = k, 2..5 = v quarters.
__global__ __launch_bounds__(384) void qkv_kernel(
    const float* __restrict__ x1p,
    const float* __restrict__ wq, const float* __restrict__ bq,
    const float* __restrict__ wk, const float* __restrict__ bk,
    const float* __restrict__ wv, const float* __restrict__ bv,
    ushort* __restrict__ qsp, ushort* __restrict__ ksp,
    ushort* __restrict__ vfrag)
{
  __shared__ float xtile[64][17];   // [ci][pix], padded (bank spread)
  const int pix0 = blockIdx.x * 16;
  const int b    = blockIdx.y;
  const int tid  = threadIdx.x;
  const int cot  = tid >> 6;        // 0..5
  const int lane = tid & 63;
  const int g    = lane >> 4;
  const int col  = lane & 15;

  const int yy = pix0 / 96, xx = pix0 - yy * 96;
  const int ro = (yy + 1) * PW + xx + 1;
  const float* xb = x1p + (size_t)b * 64 * PLANE;

  for (int idx = tid; idx < 1024; idx += 384) {
    const int ci = idx >> 4, c2 = idx & 15;
    xtile[ci][c2] = xb[(size_t)ci * PLANE + ro + c2];
  }
  __syncthreads();

  const float* wr;
  const float* bias;
  if (cot == 0)      { wr = wq + col * 64; bias = bq; }
  else if (cot == 1) { wr = wk + col * 64; bias = bk; }
  else               { wr = wv + ((cot - 2) * 16 + col) * 64; bias = bv + (cot - 2) * 16; }

  f32x4 acc = (f32x4){0.f, 0.f, 0.f, 0.f};
#pragma unroll
  for (int kt = 0; kt < 2; ++kt) {
    const float4 wa = *(const float4*)(wr + kt * 32 + 8 * g);
    const float4 wb2 = *(const float4*)(wr + kt * 32 + 8 * g + 4);
    short8 af;
    af[0] = (short)f2bf(wa.x); af[1] = (short)f2bf(wa.y);
    af[2] = (short)f2bf(wa.z); af[3] = (short)f2bf(wa.w);
    af[4] = (short)f2bf(wb2.x); af[5] = (short)f2bf(wb2.y);
    af[6] = (short)f2bf(wb2.z); af[7] = (short)f2bf(wb2.w);
    short8 bf;
#pragma unroll
    for (int jj = 0; jj < 8; ++jj)
      bf[jj] = (short)f2bf(xtile[kt * 32 + 8 * g + jj][col]);
    acc = __builtin_amdgcn_mfma_f32_16x16x32_bf16(af, bf, acc, 0, 0, 0);
  }
  if (cot < 2) {
    ushort* dst = (cot == 0 ? qsp : ksp) + ((size_t)(b * NPIX + pix0 + col)) * 32;
    const float scl = (cot == 0) ? LOG2E : 1.f;
#pragma unroll
    for (int r = 0; r < 4; ++r) {
      const int cl = 4 * g + r;
      const float val = (acc[r] + bias[cl]) * scl;
      const ushort h = f2bf(val);
      dst[cl] = h;
      dst[16 + cl] = f2bf(val - bf2f(h));
    }
  } else {
    ushort* dst = vfrag + (size_t)b * 589824;
    const int pix = pix0 + col;
    const int jt = pix >> 5, ks = (pix >> 4) & 1;
    const int lhalf = 32 * ((pix >> 3) & 1);
    const int kk = pix & 7;
#pragma unroll
    for (int r = 0; r < 4; ++r) {
      const int cl = 4 * g + r;
      const int c = (cot - 2) * 16 + cl;
      const int h = c >> 5;
      const int lA = (c & 31) + lhalf;
      dst[(size_t)((((jt * 2 + h) * 2 + ks) * 64 + lA)) * 8 + kk] =
          f2bf(acc[r] + bias[cl]);
    }
  }
}

// ---------------- flash attention (exact round-16 kernel) -------------------
// 1D grid 576: b = id&1, qb = id>>1 (batch-pinned XCD L2).
__global__ __launch_bounds__(256, 3) void attn_kernel(
    const ushort* __restrict__ qsp, const ushort* __restrict__ ksp,
    const ushort* __restrict__ vfrag, const float* __restrict__ x1p,
    const float* __restrict__ gamma_p,
    ushort* __restrict__ ofh, ushort* __restrict__ ofl)
{
  __shared__ float2 mlb[4][32];
  __shared__ float obuf[32][65];
  __shared__ float lbuf[32];

  const int id  = blockIdx.x;
  const int b   = id & 1;
  const int i0  = (id >> 1) * 32;
  const int tid = threadIdx.x;
  const int w   = tid >> 6;
  const int lane = tid & 63;
  const int li  = lane & 31;
  const int hi  = lane >> 5;

  for (int idx = tid; idx < 32 * 65; idx += 256) ((float*)obuf)[idx] = 0.f;
  if (tid < 32) lbuf[tid] = 0.f;
  __syncthreads();

  const ushort* kb    = ksp + (size_t)b * NPIX * 32;
  const ushort* vbase = vfrag + (size_t)b * 589824;

  const ushort* qrow = qsp + ((size_t)b * NPIX + i0 + li) * 32 + 8 * hi;
  const short8 qfh = *(const short8*)(qrow);
  const short8 qfl = *(const short8*)(qrow + 16);

  float m = -INFINITY;
  float lsum = 0.f;
  f32x16 acc[2] = {};

  const int jt0 = w * 72;
  const ushort* kptr = kb + (size_t)(jt0 * 32 + li) * 32 + 8 * hi;
  const ushort* vptr = vbase + ((size_t)(jt0 * 4) * 64 + lane) * 8;

  const f32x16 zf = {};

  short8 kh0 = *(const short8*)kptr;
  short8 kl0 = *(const short8*)(kptr + 16);
  f32x16 s = __builtin_amdgcn_mfma_f32_32x32x16_bf16(kh0, qfh, zf, 0, 0, 0);
  s = __builtin_amdgcn_mfma_f32_32x32x16_bf16(kl0, qfh, s, 0, 0, 0);
  s = __builtin_amdgcn_mfma_f32_32x32x16_bf16(kh0, qfl, s, 0, 0, 0);
  kptr += 1024;
  short8 kh_n = *(const short8*)kptr;
  short8 kl_n = *(const short8*)(kptr + 16);
  short8 vf00 = *(const short8*)(vptr);
  short8 vf01 = *(const short8*)(vptr + 512);
  short8 vf10 = *(const short8*)(vptr + 1024);
  short8 vf11 = *(const short8*)(vptr + 1536);

  for (int t = 0; t < 72; ++t) {
    f32x16 s_next;
    if (t < 71) {
      s_next = __builtin_amdgcn_mfma_f32_32x32x16_bf16(kh_n, qfh, zf, 0, 0, 0);
      s_next = __builtin_amdgcn_mfma_f32_32x32x16_bf16(kl_n, qfh, s_next, 0, 0, 0);
      s_next = __builtin_amdgcn_mfma_f32_32x32x16_bf16(kh_n, qfl, s_next, 0, 0, 0);
    }

    short8 kh_p, kl_p, v00n, v01n, v10n, v11n;
    if (t < 70) {
      kptr += 1024;
      kh_p = *(const short8*)kptr;
      kl_p = *(const short8*)(kptr + 16);
    }
    if (t < 71) {
      vptr += 2048;
      v00n = *(const short8*)(vptr);
      v01n = *(const short8*)(vptr + 512);
      v10n = *(const short8*)(vptr + 1024);
      v11n = *(const short8*)(vptr + 1536);
    }

    float pm, q1, q2, q3, q4;
    pm = max3f(s[0], s[1], s[2]);
    q1 = max3f(s[3], s[4], s[5]);
    q2 = max3f(s[6], s[7], s[8]);
    q3 = max3f(s[9], s[10], s[11]);
    q4 = max3f(s[12], s[13], s[14]);
    pm = max3f(pm, q1, q2);
    pm = max3f(pm, q3, q4);
    pm = fmaxf(pm, s[15]);
    {
      float o = pm;
      asm("v_permlane32_swap_b32 %0, %1" : "+v"(o), "+v"(pm));
      pm = fmaxf(pm, o);
    }

    if (__any(pm > m + 8.f)) {   // defer-max rescale (T13)
      const float mnew = fmaxf(m, pm);
      const float corr = __builtin_amdgcn_exp2f(m - mnew);
      lsum *= corr;
      acc[0] *= corr;
      acc[1] *= corr;
      m = mnew;
    }

#pragma unroll
    for (int r = 0; r < 16; ++r) s[r] = __builtin_amdgcn_exp2f(s[r] - m);
    lsum += (((s[0] + s[1]) + (s[2] + s[3])) + ((s[4] + s[5]) + (s[6] + s[7]))) +
            (((s[8] + s[9]) + (s[10] + s[11])) + ((s[12] + s[13]) + (s[14] + s[15])));

    u32 c01, c23, c45, c67, d01, d23, d45, d67;
    asm("v_cvt_pk_bf16_f32 %0, %1, %2" : "=v"(c01) : "v"(s[0]),  "v"(s[1]));
    asm("v_cvt_pk_bf16_f32 %0, %1, %2" : "=v"(c23) : "v"(s[2]),  "v"(s[3]));
    asm("v_cvt_pk_bf16_f32 %0, %1, %2" : "=v"(c45) : "v"(s[4]),  "v"(s[5]));
    asm("v_cvt_pk_bf16_f32 %0, %1, %2" : "=v"(c67) : "v"(s[6]),  "v"(s[7]));
    asm("v_cvt_pk_bf16_f32 %0, %1, %2" : "=v"(d01) : "v"(s[8]),  "v"(s[9]));
    asm("v_cvt_pk_bf16_f32 %0, %1, %2" : "=v"(d23) : "v"(s[10]), "v"(s[11]));
    asm("v_cvt_pk_bf16_f32 %0, %1, %2" : "=v"(d45) : "v"(s[12]), "v"(s[13]));
    asm("v_cvt_pk_bf16_f32 %0, %1, %2" : "=v"(d67) : "v"(s[14]), "v"(s[15]));
    asm("v_permlane32_swap_b32 %0, %1" : "+v"(c45), "+v"(c01));
    asm("v_permlane32_swap_b32 %0, %1" : "+v"(c67), "+v"(c23));
    asm("v_permlane32_swap_b32 %0, %1" : "+v"(d45), "+v"(d01));
    asm("v_permlane32_swap_b32 %0, %1" : "+v"(d67), "+v"(d23));
    const short8 pf1 = __builtin_bit_cast(short8, (u32x4){c01, c23, c45, c67});
    const short8 pf2 = __builtin_bit_cast(short8, (u32x4){d01, d23, d45, d67});

    acc[0] = __builtin_amdgcn_mfma_f32_32x32x16_bf16(vf00, pf1, acc[0], 0, 0, 0);
    acc[0] = __builtin_amdgcn_mfma_f32_32x32x16_bf16(vf01, pf2, acc[0], 0, 0, 0);
    acc[1] = __builtin_amdgcn_mfma_f32_32x32x16_bf16(vf10, pf1, acc[1], 0, 0, 0);
    acc[1] = __builtin_amdgcn_mfma_f32_32x32x16_bf16(vf11, pf2, acc[1], 0, 0, 0);

    if (t < 71) {
      s = s_next;
      vf00 = v00n; vf01 = v01n; vf10 = v10n; vf11 = v11n;
    }
    if (t < 70) { kh_n = kh_p; kl_n = kl_p; }
  }

  {
    float o = lsum;
    asm("v_permlane32_swap_b32 %0, %1" : "+v"(o), "+v"(lsum));
    lsum = lsum + o;
  }

  if (hi == 0) { float2 t2; t2.x = m; t2.y = lsum; mlb[w][li] = t2; }
  __syncthreads();
  float M = -INFINITY;
#pragma unroll
  for (int ww = 0; ww < 4; ++ww) M = fmaxf(M, mlb[ww][li].x);
  const float f = __builtin_amdgcn_exp2f(m - M);
  if (hi == 0) atomicAdd(&lbuf[li], lsum * f);
#pragma unroll
  for (int hh = 0; hh < 2; ++hh)
#pragma unroll
    for (int r = 0; r < 16; ++r) {
      const int c = (r & 3) + 8 * (r >> 2) + 4 * hi + 32 * hh;
      atomicAdd(&obuf[li][c], acc[hh][r] * f);
    }
  __syncthreads();

  const float gm = gamma_p[0];
  for (int idx = tid; idx < 2048; idx += 256) {
    const int il = idx & 31, c = idx >> 5;
    const int p = i0 + il;
    const int y = p / 96, x = p - y * 96;
    const int ro = (y + 1) * PW + x + 1;
    const float val = obuf[il][c] / lbuf[il] * gm +
                      x1p[(size_t)(b * 64 + c) * PLANE + ro];
    const ushort h = f2bf(val);
    const size_t d = (size_t)(b * 64 + c) * PLANEB + ro;
    ofh[d] = h;
    ofl[d] = f2bf(val - bf2f(h));
  }
}

// ---------------------------------------------------------------------------
extern "C" void kernel_launch(void* const* d_in, const int* in_sizes, int n_in,
                              void* d_out, int out_size, void* d_ws, size_t ws_size,
                              hipStream_t stream) {
  const float* x      = (const float*)d_in[0];
  const float* w_pre  = (const float*)d_in[1];
  const float* bn1_g  = (const float*)d_in[2];
  const float* bn1_b  = (const float*)d_in[3];
  const float* bn1_m  = (const float*)d_in[4];
  const float* bn1_v  = (const float*)d_in[5];
  const float* wq     = (const float*)d_in[6];
  const float* bq     = (const float*)d_in[7];
  const float* wk     = (const float*)d_in[8];
  const float* bk     = (const float*)d_in[9];
  const float* wv     = (const float*)d_in[10];
  const float* bv     = (const float*)d_in[11];
  const float* w_fin  = (const float*)d_in[12];
  const float* bn2_g  = (const float*)d_in[13];
  const float* bn2_b  = (const float*)d_in[14];
  const float* bn2_m  = (const float*)d_in[15];
  const float* bn2_v  = (const float*)d_in[16];
  const float* gamma  = (const float*)d_in[17];
  float* out = (float*)d_out;

  char* ws = (char*)d_ws;
  float*  x1p  = (float*)(ws);                       // 4,917,248 B
  ushort* xh   = (ushort*)(ws + 4917248);            // 2,459,648 B
  ushort* xl   = (ushort*)(ws + 7376896);            // 2,459,648 B
  ushort* qsp  = (ushort*)(ws + 9836544);            // 1,179,648 B
  ushort* ksp  = (ushort*)(ws + 11016192);           // 1,179,648 B
  ushort* vfr  = (ushort*)(ws + 12195840);           // 2,359,296 B
  ushort* fpre = (ushort*)(ws + 14555136);           //   147,456 B
  ushort* ffin = (ushort*)(ws + 14702592);           //   147,456 B -> end 14,850,048
  ushort* ofh = xh;   // xh/xl dead after conv1; reuse for attn output planes
  ushort* ofl = xl;

  // zero bf16 plane region (pad rings must be 0; interiors rewritten each call)
  hipMemsetAsync(ws + 4917248, 0, 4919296, stream);

  wprep<<<dim3(144, 2), 256, 0, stream>>>(w_pre, w_fin, fpre, ffin);
  pad_split<<<dim3(128), 256, 0, stream>>>(x, xh, xl);
  conv3x3_mfma<true><<<dim3(147, 2), 256, 0, stream>>>(
      xh, xl, fpre, bn1_g, bn1_b, bn1_m, bn1_v, x1p);
  qkv_kernel<<<dim3(576, 2), 384, 0, stream>>>(
      x1p, wq, bq, wk, bk, wv, bv, qsp, ksp, vfr);
  attn_kernel<<<dim3(576), 256, 0, stream>>>(
      qsp, ksp, vfr, x1p, gamma, ofh, ofl);
  conv3x3_mfma<false><<<dim3(147, 2), 256, 0, stream>>>(
      ofh, ofl, ffin, bn2_g, bn2_b, bn2_m, bn2_v, out);
}